// Round 9
// baseline (637.198 us; speedup 1.0000x reference)
//
#include <hip/hip_runtime.h>
#include <hip/hip_bf16.h>

#define N_NODES 10000
#define N_EDGES 160000
#define HID 300
#define HIDP 304   // padded hidden dim
#define NPARTB (N_EDGES - N_NODES)   // 150000 independent rows
#define RB 48      // rows per GCN unit (3 M-tiles); 150000/48 = 3125 exact
#define KS 328     // H-plane k-stride in shorts
#define PARTB_BLOCKS 3125
#define GEMMA_BLOCKS 209   // ceil(10000/48)
#define FILL_BLOCKS 313    // ceil(160000/512)
#define MEGA_BLOCKS (PARTB_BLOCKS + GEMMA_BLOCKS + FILL_BLOCKS)

typedef __attribute__((ext_vector_type(8))) short short8;
typedef __attribute__((ext_vector_type(4))) float f32x4;

#define MFMA_B16(a, b, c) __builtin_amdgcn_mfma_f32_16x16x32_bf16(a, b, c, 0, 0, 0)

__device__ __forceinline__ short bf16r(float x) {
    unsigned u = __float_as_uint(x);
    return (short)((u + 0x7fffu + ((u >> 16) & 1u)) >> 16);
}

__device__ __forceinline__ float b2f(unsigned short u) {
    return __uint_as_float(((unsigned)u) << 16);
}

__device__ __forceinline__ void split1(float x, short& hi, short& lo) {
    short h = bf16r(x);
    float hf = __uint_as_float(((unsigned)(unsigned short)h) << 16);
    hi = h;
    lo = bf16r(x - hf);
}

// ---------------------------------------------------------------------------
// k_prep: weight pre-split (layout verified R2-R7) + degree count, one launch.
// ---------------------------------------------------------------------------
__global__ void k_prep(const float* __restrict__ g0w, const float* __restrict__ gw,
                       short* __restrict__ wt0, short* __restrict__ wtl,
                       const int* __restrict__ col, int* __restrict__ cnt) {
    int idx = blockIdx.x * 256 + threadIdx.x;
    if (idx < N_EDGES) atomicAdd(&cnt[col[idx]], 1);
    if (idx < 1216) {
        int n16 = idx & 15, q = (idx >> 4) & 3, nt = idx >> 6;
        int n = nt * 16 + n16;
        short* hd = wt0 + (size_t)(nt * 8 + q) * 128 + n16 * 8;
        short* ld = wt0 + (size_t)(nt * 8 + 4 + q) * 128 + n16 * 8;
#pragma unroll
        for (int j = 0; j < 8; ++j) {
            int k = q * 8 + j;
            float f = (n < HID) ? g0w[k * HID + n] : 0.0f;
            short hi, lo;
            split1(f, hi, lo);
            hd[j] = hi;
            ld[j] = lo;
        }
    } else if (idx < 1216 + 48640) {
        int i = idx - 1216;
        int n16 = i & 15; i >>= 4;
        int q = i & 3; i >>= 2;
        int nt = i % 19; i /= 19;
        int chunk = i % 10;
        int l = i / 10;
        int n = nt * 16 + n16;
        int cnt_idx = chunk * 19 + nt;
        short* base = wtl + (size_t)l * 194560;
        short* hd = base + (size_t)(cnt_idx * 8 + q) * 128 + n16 * 8;
        short* ld = base + (size_t)(cnt_idx * 8 + 4 + q) * 128 + n16 * 8;
#pragma unroll
        for (int j = 0; j < 8; ++j) {
            int k = chunk * 32 + q * 8 + j;
            float f = (k < HID && n < HID) ? gw[((size_t)l * HID + k) * HID + n] : 0.0f;
            short hi, lo;
            split1(f, hi, lo);
            hd[j] = hi;
            ld[j] = lo;
        }
    }
}

// k_scan (verified R7): prefix sum + dinv/selfnorm
__global__ void k_scan(const int* __restrict__ cnt, int* __restrict__ col_start,
                       int* __restrict__ cursor, float* __restrict__ dinv,
                       float* __restrict__ selfnorm) {
    __shared__ int wsum[4];
    int t = threadIdx.x;
    int lane = t & 63, w = t >> 6;
    int carry = 0;
    for (int base = 0; base < N_NODES; base += 256) {
        int i = base + t;
        int v = (i < N_NODES) ? cnt[i] : 0;
        int s = v;
#pragma unroll
        for (int d = 1; d < 64; d <<= 1) {
            int n = __shfl_up(s, d, 64);
            if (lane >= d) s += n;
        }
        if (lane == 63) wsum[w] = s;
        __syncthreads();
        int woff = 0;
#pragma unroll
        for (int k = 0; k < 4; ++k)
            if (k < w) woff += wsum[k];
        int total = wsum[0] + wsum[1] + wsum[2] + wsum[3];
        if (i < N_NODES) {
            int excl = carry + woff + s - v;
            col_start[i] = excl;
            cursor[i] = excl;
            float dd = (float)v + 1.0f;
            dinv[i] = rsqrtf(dd);
            selfnorm[i] = 1.0f / dd;
        }
        carry += total;
        __syncthreads();
    }
    if (t == 0) col_start[N_NODES] = carry;
}

// ---------------------------------------------------------------------------
// GCN core (2-term split, single bf16 A-plane in LDS, 3 M-tiles = 48 rows).
// Runtime chunk loop (unroll 1 — R5/R6 spill lesson), single-buffered.
// Regs: acc 36 (AGPR) + A 12 + B 12 + addr ≈ 75 — fits launch_bounds(512,6)
// budget of 85 (3 blocks/CU = 24 waves/CU).
// ---------------------------------------------------------------------------
template <int NTC>
__device__ __forceinline__ void kloop(const short* __restrict__ wp, int nch,
                                      const short* Hh,
                                      int nt0, int quad, int l16,
                                      f32x4 (&acc)[3][3]) {
#pragma unroll
    for (int mt = 0; mt < 3; ++mt)
#pragma unroll
        for (int i = 0; i < NTC; ++i)
#pragma unroll
            for (int r = 0; r < 4; ++r) acc[mt][i][r] = 0.0f;
#pragma unroll 1
    for (int c = 0; c < nch; ++c) {
        const short* cb = wp + (size_t)(c * 19 + nt0) * 1024 + quad * 128 + l16 * 8;
        short8 ah[3];
#pragma unroll
        for (int mt = 0; mt < 3; ++mt)
            ah[mt] = *(const short8*)&Hh[(mt * 16 + l16) * KS + c * 32 + quad * 8];
        short8 bb[NTC];
#pragma unroll
        for (int i = 0; i < NTC; ++i) bb[i] = *(const short8*)(cb + (size_t)i * 1024);
#pragma unroll
        for (int mt = 0; mt < 3; ++mt)
#pragma unroll
            for (int i = 0; i < NTC; ++i)
                acc[mt][i] = MFMA_B16(ah[mt], bb[i], acc[mt][i]);
#pragma unroll
        for (int i = 0; i < NTC; ++i) bb[i] = *(const short8*)(cb + (size_t)i * 1024 + 512);
#pragma unroll
        for (int mt = 0; mt < 3; ++mt)
#pragma unroll
            for (int i = 0; i < NTC; ++i)
                acc[mt][i] = MFMA_B16(ah[mt], bb[i], acc[mt][i]);
    }
}

template <int NTC>
__device__ __forceinline__ void gcn_epilogue(const float* __restrict__ bias,
                                             int nt0, int quad, int l16,
                                             f32x4 (&acc)[3][3], short* Hh) {
#pragma unroll
    for (int i = 0; i < NTC; ++i) {
        int c = (nt0 + i) * 16 + l16;
        float b = (c < HID) ? bias[c] : 0.0f;
#pragma unroll
        for (int mt = 0; mt < 3; ++mt)
#pragma unroll
            for (int r = 0; r < 4; ++r) {
                float v = fmaxf(acc[mt][i][r] + b, 0.0f);
                Hh[(mt * 16 + quad * 4 + r) * KS + c] = bf16r(v);
            }
    }
}

template <int NTC>
__device__ __forceinline__ void gcn_final(const float* __restrict__ bias,
                                          int nt0, int quad, int l16, int slot,
                                          f32x4 (&acc)[3][3],
                                          float* __restrict__ g_part) {
#pragma unroll
    for (int i = 0; i < NTC; ++i) {
        int c = (nt0 + i) * 16 + l16;
        float b = (c < HID) ? bias[c] : 0.0f;
        float s = 0.0f;
#pragma unroll
        for (int mt = 0; mt < 3; ++mt)
#pragma unroll
            for (int r = 0; r < 4; ++r) s += fmaxf(acc[mt][i][r] + b, 0.0f);
        s += __shfl_xor(s, 16, 64);
        s += __shfl_xor(s, 32, 64);
        if (quad == 0 && c < HID)
            atomicAdd(&g_part[slot * HIDP + c], s);
    }
}

template <int NTC>
__device__ __forceinline__ void gemm_out(int base, int nt0, int quad, int l16,
                                         f32x4 (&acc)[3][3],
                                         unsigned short* __restrict__ HW) {
#pragma unroll
    for (int i = 0; i < NTC; ++i) {
        int c = (nt0 + i) * 16 + l16;
#pragma unroll
        for (int mt = 0; mt < 3; ++mt)
#pragma unroll
            for (int r = 0; r < 4; ++r) {
                int gm = base + mt * 16 + quad * 4 + r;
                if (gm < N_NODES)
                    HW[(size_t)gm * HIDP + c] = (unsigned short)bf16r(acc[mt][i][r]);
            }
    }
}

// ---------------------------------------------------------------------------
// k_mega: partB (3125) U gemmA-L0 (209) U CSR-fill (313) — one launch;
// the small units fill idle CUs during partB's run.
// ---------------------------------------------------------------------------
__global__ __launch_bounds__(512, 6) void k_mega(
    const float* __restrict__ edge_attr,
    const float* __restrict__ edge_w,
    const float* __restrict__ edge_b,
    const short* __restrict__ wt0,
    const short* __restrict__ wtl,
    const float* __restrict__ gcn0_b,
    const float* __restrict__ gcn_b,
    float* __restrict__ g_part,
    unsigned short* __restrict__ hw0,
    const int* __restrict__ row,
    const int* __restrict__ col,
    int* __restrict__ cursor,
    const float* __restrict__ dinv,
    int2* __restrict__ edge_pack) {
    __shared__ short Hh[RB * KS];   // 31488 B
    int bid = blockIdx.x, t = threadIdx.x;
    int lane = t & 63, w = t >> 6;
    int l16 = lane & 15, quad = lane >> 4;
    int nt0 = (w < 3) ? w * 3 : 9 + (w - 3) * 2;

    if (bid < PARTB_BLOCKS) {
        // ---------------- Part B unit (fused 5-layer) ----------------
        int base = N_NODES + bid * RB;
        if (t < 384) {
            int r = t >> 3, c4 = (t & 7) * 4;
            const float* ar = edge_attr + (size_t)(base + r) * 3;
            float a0 = ar[0], a1 = ar[1], a2 = ar[2];
#pragma unroll
            for (int j = 0; j < 4; ++j) {
                int cc = c4 + j;
                float v = edge_b[cc];
                v = fmaf(a0, edge_w[cc], v);
                v = fmaf(a1, edge_w[32 + cc], v);
                v = fmaf(a2, edge_w[64 + cc], v);
                Hh[r * KS + cc] = bf16r(v);
            }
        }
        for (int i = t; i < RB * 24; i += 512) {
            int r = i / 24, k = 304 + i % 24;
            Hh[r * KS + k] = 0;
        }
        __syncthreads();

        f32x4 acc[3][3];
        if (w < 3) kloop<3>(wt0, 1, Hh, nt0, quad, l16, acc);
        else       kloop<2>(wt0, 1, Hh, nt0, quad, l16, acc);
        __syncthreads();
        if (w < 3) gcn_epilogue<3>(gcn0_b, nt0, quad, l16, acc, Hh);
        else       gcn_epilogue<2>(gcn0_b, nt0, quad, l16, acc, Hh);
        __syncthreads();

        for (int l = 0; l < 4; ++l) {
            const short* wp = wtl + (size_t)l * 194560;
            const float* bias = gcn_b + l * HID;
            if (w < 3) kloop<3>(wp, 10, Hh, nt0, quad, l16, acc);
            else       kloop<2>(wp, 10, Hh, nt0, quad, l16, acc);
            __syncthreads();
            if (l < 3) {
                if (w < 3) gcn_epilogue<3>(bias, nt0, quad, l16, acc, Hh);
                else       gcn_epilogue<2>(bias, nt0, quad, l16, acc, Hh);
                __syncthreads();
            } else {
                int slot = (bid + w) & 63;
                if (w < 3) gcn_final<3>(bias, nt0, quad, l16, slot, acc, g_part);
                else       gcn_final<2>(bias, nt0, quad, l16, slot, acc, g_part);
            }
        }
    } else if (bid < PARTB_BLOCKS + GEMMA_BLOCKS) {
        // ---------------- Part A layer-0 GEMM: hw0 = e @ W0 ----------------
        int base = (bid - PARTB_BLOCKS) * RB;
        if (t < 384) {
            int r = t >> 3, c4 = (t & 7) * 4;
            int gr = base + r;
            float a0 = 0.f, a1 = 0.f, a2 = 0.f;
            if (gr < N_NODES) {
                const float* ar = edge_attr + (size_t)gr * 3;
                a0 = ar[0]; a1 = ar[1]; a2 = ar[2];
            }
#pragma unroll
            for (int j = 0; j < 4; ++j) {
                int cc = c4 + j;
                float v = 0.0f;
                if (gr < N_NODES) {
                    v = edge_b[cc];
                    v = fmaf(a0, edge_w[cc], v);
                    v = fmaf(a1, edge_w[32 + cc], v);
                    v = fmaf(a2, edge_w[64 + cc], v);
                }
                Hh[r * KS + cc] = bf16r(v);
            }
        }
        for (int i = t; i < RB * 24; i += 512) {
            int r = i / 24, k = 304 + i % 24;
            Hh[r * KS + k] = 0;
        }
        __syncthreads();
        f32x4 acc[3][3];
        if (w < 3) kloop<3>(wt0, 1, Hh, nt0, quad, l16, acc);
        else       kloop<2>(wt0, 1, Hh, nt0, quad, l16, acc);
        if (w < 3) gemm_out<3>(base, nt0, quad, l16, acc, hw0);
        else       gemm_out<2>(base, nt0, quad, l16, acc, hw0);
    } else {
        // ---------------- CSR fill (row, norm) ----------------
        int e = (bid - PARTB_BLOCKS - GEMMA_BLOCKS) * 512 + t;
        if (e < N_EDGES) {
            int c = col[e], r = row[e];
            int p = atomicAdd(&cursor[c], 1);
            edge_pack[p] = make_int2(r, __float_as_int(dinv[r] * dinv[c]));
        }
    }
}

// ---------------------------------------------------------------------------
// agg of 6 rows per wave into v[5]; shared by k_fuse / k_last.
// ---------------------------------------------------------------------------
__device__ __forceinline__ void agg_row(int c, int lane,
                                        const unsigned short* __restrict__ hw_in,
                                        const int* __restrict__ col_start,
                                        const int2* __restrict__ edge_pack,
                                        float (&v)[5]) {
#pragma unroll
    for (int jj = 0; jj < 5; ++jj) v[jj] = 0.0f;
    int beg = col_start[c], end = col_start[c + 1];
    int i = beg;
    for (; i + 4 <= end; i += 4) {
        int2 e0 = edge_pack[i], e1 = edge_pack[i + 1];
        int2 e2 = edge_pack[i + 2], e3 = edge_pack[i + 3];
        const unsigned short* h0 = hw_in + (size_t)e0.x * HIDP;
        const unsigned short* h1 = hw_in + (size_t)e1.x * HIDP;
        const unsigned short* h2 = hw_in + (size_t)e2.x * HIDP;
        const unsigned short* h3 = hw_in + (size_t)e3.x * HIDP;
        float n0 = __int_as_float(e0.y), n1 = __int_as_float(e1.y);
        float n2 = __int_as_float(e2.y), n3 = __int_as_float(e3.y);
#pragma unroll
        for (int jj = 0; jj < 5; ++jj) {
            int cc = lane + 64 * jj;
            if (cc < HIDP) {
                float s = v[jj];
                s = fmaf(n0, b2f(h0[cc]), s);
                s = fmaf(n1, b2f(h1[cc]), s);
                s = fmaf(n2, b2f(h2[cc]), s);
                s = fmaf(n3, b2f(h3[cc]), s);
                v[jj] = s;
            }
        }
    }
    for (; i < end; ++i) {
        int2 e0 = edge_pack[i];
        const unsigned short* h0 = hw_in + (size_t)e0.x * HIDP;
        float n0 = __int_as_float(e0.y);
#pragma unroll
        for (int jj = 0; jj < 5; ++jj) {
            int cc = lane + 64 * jj;
            if (cc < HIDP) v[jj] = fmaf(n0, b2f(h0[cc]), v[jj]);
        }
    }
}

// ---------------------------------------------------------------------------
// k_fuse: agg(prev hw) -> relu+bias -> stage LDS -> gemm -> next hw.
// No cross-block dependency (hw_in complete from previous launch).
// ---------------------------------------------------------------------------
__global__ __launch_bounds__(512, 6) void k_fuse(
    const unsigned short* __restrict__ hw_in,
    const int* __restrict__ col_start,
    const int2* __restrict__ edge_pack,
    const float* __restrict__ selfnorm,
    const float* __restrict__ bias,
    const short* __restrict__ wt,
    unsigned short* __restrict__ hw_out) {
    __shared__ short Hh[RB * KS];
    int t = threadIdx.x;
    int lane = t & 63, w = t >> 6;
    int l16 = lane & 15, quad = lane >> 4;
    int base = blockIdx.x * RB;
    int nt0 = (w < 3) ? w * 3 : 9 + (w - 3) * 2;

#pragma unroll 1
    for (int j = 0; j < 6; ++j) {
        int r = w * 6 + j;
        int c = base + r;
        if (c < N_NODES) {
            float v[5];
            agg_row(c, lane, hw_in, col_start, edge_pack, v);
            float sn = selfnorm[c];
            const unsigned short* sp = hw_in + (size_t)c * HIDP;
#pragma unroll
            for (int jj = 0; jj < 5; ++jj) {
                int cc = lane + 64 * jj;
                if (cc < HIDP) {
                    float h = v[jj] + sn * b2f(sp[cc]) + ((cc < HID) ? bias[cc] : 0.0f);
                    Hh[r * KS + cc] = bf16r(fmaxf(h, 0.0f));
                }
            }
        } else {
#pragma unroll
            for (int jj = 0; jj < 5; ++jj) {
                int cc = lane + 64 * jj;
                if (cc < HIDP) Hh[r * KS + cc] = 0;
            }
        }
    }
    for (int i = t; i < RB * 24; i += 512) {
        int r = i / 24, k = 304 + i % 24;
        Hh[r * KS + k] = 0;
    }
    __syncthreads();

    f32x4 acc[3][3];
    if (w < 3) kloop<3>(wt, 10, Hh, nt0, quad, l16, acc);
    else       kloop<2>(wt, 10, Hh, nt0, quad, l16, acc);
    if (w < 3) gemm_out<3>(base, nt0, quad, l16, acc, hw_out);
    else       gemm_out<2>(base, nt0, quad, l16, acc, hw_out);
}

// ---------------------------------------------------------------------------
// k_last: final agg (layer 5) + column sums straight into g_sum.
// ---------------------------------------------------------------------------
__global__ __launch_bounds__(512) void k_last(
    const unsigned short* __restrict__ hw_in,
    const int* __restrict__ col_start,
    const int2* __restrict__ edge_pack,
    const float* __restrict__ selfnorm,
    const float* __restrict__ bias,
    float* __restrict__ g_sum) {
    __shared__ float red[8 * 320];
    int t = threadIdx.x;
    int lane = t & 63, w = t >> 6;
    int base = blockIdx.x * RB;

    float s[5] = {0.0f, 0.0f, 0.0f, 0.0f, 0.0f};
#pragma unroll 1
    for (int j = 0; j < 6; ++j) {
        int c = base + w * 6 + j;
        if (c < N_NODES) {
            float v[5];
            agg_row(c, lane, hw_in, col_start, edge_pack, v);
            float sn = selfnorm[c];
            const unsigned short* sp = hw_in + (size_t)c * HIDP;
#pragma unroll
            for (int jj = 0; jj < 5; ++jj) {
                int cc = lane + 64 * jj;
                if (cc < HID) {
                    float h = v[jj] + sn * b2f(sp[cc]) + bias[cc];
                    s[jj] += fmaxf(h, 0.0f);
                }
            }
        }
    }
#pragma unroll
    for (int jj = 0; jj < 5; ++jj) red[w * 320 + lane + 64 * jj] = s[jj];
    __syncthreads();
    if (w == 0) {
#pragma unroll
        for (int jj = 0; jj < 5; ++jj) {
            int cc = lane + 64 * jj;
            if (cc < HID) {
                float tot = 0.0f;
#pragma unroll
                for (int g = 0; g < 8; ++g) tot += red[g * 320 + cc];
                atomicAdd(&g_sum[cc], tot);
            }
        }
    }
}

// head: fold g_part + g_sum -> mean -> lin1 relu -> lin2
__global__ void k_head(const float* __restrict__ g_sum,
                       const float* __restrict__ g_part,
                       const float* __restrict__ lin1_w, const float* __restrict__ lin1_b,
                       const float* __restrict__ lin2_w, const float* __restrict__ lin2_b,
                       float* __restrict__ out) {
    __shared__ float gm[HID];
    __shared__ float g2[32];
    int t = threadIdx.x;
    const float inv = 1.0f / (float)N_EDGES;
    for (int c = t; c < HID; c += 256) {
        float s = g_sum[c];
        for (int g = 0; g < 64; ++g) s += g_part[g * HIDP + c];
        gm[c] = s * inv;
    }
    __syncthreads();
    if (t < 32) {
        float a = lin1_b[t];
        for (int d = 0; d < HID; ++d) a = fmaf(gm[d], lin1_w[d * 32 + t], a);
        g2[t] = fmaxf(a, 0.0f);
    }
    __syncthreads();
    if (t < 2) {
        float p = lin2_b[t];
        for (int j = 0; j < 32; ++j) p = fmaf(g2[j], lin2_w[j * 2 + t], p);
        out[t] = p;
    }
}

// ---------------------------------------------------------------------------

extern "C" void kernel_launch(void* const* d_in, const int* in_sizes, int n_in,
                              void* d_out, int out_size, void* d_ws, size_t ws_size,
                              hipStream_t stream) {
    (void)in_sizes; (void)n_in; (void)out_size; (void)ws_size;
    const int* edge_index = (const int*)d_in[1];
    const float* edge_attr = (const float*)d_in[2];
    const float* edge_w = (const float*)d_in[6];
    const float* edge_b = (const float*)d_in[7];
    const float* gcn0_w = (const float*)d_in[8];
    const float* gcn0_b = (const float*)d_in[9];
    const float* gcn_w = (const float*)d_in[10];
    const float* gcn_b = (const float*)d_in[11];
    const float* lin1_w = (const float*)d_in[12];
    const float* lin1_b = (const float*)d_in[13];
    const float* lin2_w = (const float*)d_in[14];
    const float* lin2_b = (const float*)d_in[15];

    char* ws = (char*)d_ws;
    size_t off = 0;
    auto alloc = [&](size_t bytes) {
        void* p = ws + off;
        off = (off + bytes + 255) & ~(size_t)255;
        return p;
    };
    unsigned short* hwA = (unsigned short*)alloc((size_t)N_NODES * HIDP * 2);
    unsigned short* hwB = (unsigned short*)alloc((size_t)N_NODES * HIDP * 2);
    int2* edge_pack = (int2*)alloc((size_t)N_EDGES * 8);
    int* cnt = (int*)alloc((size_t)N_NODES * 4);
    int* col_start = (int*)alloc((size_t)(N_NODES + 1) * 4);
    int* cursor = (int*)alloc((size_t)N_NODES * 4);
    float* dinv = (float*)alloc((size_t)N_NODES * 4);
    float* selfnorm = (float*)alloc((size_t)N_NODES * 4);
    float* g_sum = (float*)alloc((size_t)HIDP * 4);
    short* wt0 = (short*)alloc((size_t)38912);
    short* wtl = (short*)alloc((size_t)4 * 389120);
    float* g_part = (float*)alloc((size_t)64 * HIDP * 4);

    const int* row = edge_index;
    const int* col = edge_index + N_EDGES;

    hipMemsetAsync(cnt, 0, N_NODES * 4, stream);
    hipMemsetAsync(g_sum, 0, HIDP * 4, stream);
    hipMemsetAsync(g_part, 0, 64 * HIDP * 4, stream);

    // prep: weight split + degree count (one launch)
    k_prep<<<(N_EDGES + 255) / 256, 256, 0, stream>>>(gcn0_w, gcn_w, wt0, wtl, col, cnt);
    k_scan<<<1, 256, 0, stream>>>(cnt, col_start, cursor, dinv, selfnorm);

    // mega: partB (5 fused layers) + Part-A L0 gemm + CSR fill
    k_mega<<<MEGA_BLOCKS, 512, 0, stream>>>(edge_attr, edge_w, edge_b, wt0, wtl,
                                            gcn0_b, gcn_b, g_part, hwA,
                                            row, col, cursor, dinv, edge_pack);

    // Part A layers 1..4: fused agg+gemm per layer
    k_fuse<<<GEMMA_BLOCKS, 512, 0, stream>>>(hwA, col_start, edge_pack, selfnorm,
                                             gcn0_b, wtl + (size_t)0 * 194560, hwB);
    k_fuse<<<GEMMA_BLOCKS, 512, 0, stream>>>(hwB, col_start, edge_pack, selfnorm,
                                             gcn_b + 0 * HID, wtl + (size_t)1 * 194560, hwA);
    k_fuse<<<GEMMA_BLOCKS, 512, 0, stream>>>(hwA, col_start, edge_pack, selfnorm,
                                             gcn_b + 1 * HID, wtl + (size_t)2 * 194560, hwB);
    k_fuse<<<GEMMA_BLOCKS, 512, 0, stream>>>(hwB, col_start, edge_pack, selfnorm,
                                             gcn_b + 2 * HID, wtl + (size_t)3 * 194560, hwA);
    // final agg + colsum
    k_last<<<GEMMA_BLOCKS, 512, 0, stream>>>(hwA, col_start, edge_pack, selfnorm,
                                             gcn_b + 3 * HID, g_sum);
    k_head<<<1, 256, 0, stream>>>(g_sum, g_part, lin1_w, lin1_b, lin2_w, lin2_b,
                                  (float*)d_out);
}

// Round 10
// 590.857 us; speedup vs baseline: 1.0784x; 1.0784x over previous
//
#include <hip/hip_runtime.h>
#include <hip/hip_bf16.h>

#define N_NODES 10000
#define N_EDGES 160000
#define HID 300
#define HIDP 304
#define NPARTB (N_EDGES - N_NODES)   // 150000
#define KS 328                        // H-plane k-stride in shorts
#define RBM 96                        // mega partB rows/block (6 M-tiles)
#define RBF 48                        // fuse rows/block (3 M-tiles)
#define PARTB_BLOCKS 1563             // ceil(150000/96)
#define GEMMA_BLOCKS 105              // ceil(10000/96)
#define FILL_BLOCKS 250               // 160000/640
#define MEGA_BLOCKS (PARTB_BLOCKS + GEMMA_BLOCKS + FILL_BLOCKS)
#define FUSE_BLOCKS 209               // ceil(10000/48)

typedef __attribute__((ext_vector_type(8))) short short8;
typedef __attribute__((ext_vector_type(4))) float f32x4;

#define MFMA_B16(a, b, c) __builtin_amdgcn_mfma_f32_16x16x32_bf16(a, b, c, 0, 0, 0)

__device__ __forceinline__ short bf16r(float x) {
    unsigned u = __float_as_uint(x);
    return (short)((u + 0x7fffu + ((u >> 16) & 1u)) >> 16);
}
__device__ __forceinline__ float b2f(unsigned short u) {
    return __uint_as_float(((unsigned)u) << 16);
}
__device__ __forceinline__ void split1(float x, short& hi, short& lo) {
    short h = bf16r(x);
    float hf = __uint_as_float(((unsigned)(unsigned short)h) << 16);
    hi = h;
    lo = bf16r(x - hf);
}

// ---------------------------------------------------------------------------
// k_prep: weight pre-split (layout verified R2-R9) + degree count.
// ---------------------------------------------------------------------------
__global__ void k_prep(const float* __restrict__ g0w, const float* __restrict__ gw,
                       short* __restrict__ wt0, short* __restrict__ wtl,
                       const int* __restrict__ col, int* __restrict__ cnt) {
    int idx = blockIdx.x * 256 + threadIdx.x;
    if (idx < N_EDGES) atomicAdd(&cnt[col[idx]], 1);
    if (idx < 1216) {
        int n16 = idx & 15, q = (idx >> 4) & 3, nt = idx >> 6;
        int n = nt * 16 + n16;
        short* hd = wt0 + (size_t)(nt * 8 + q) * 128 + n16 * 8;
        short* ld = wt0 + (size_t)(nt * 8 + 4 + q) * 128 + n16 * 8;
#pragma unroll
        for (int j = 0; j < 8; ++j) {
            int k = q * 8 + j;
            float f = (n < HID) ? g0w[k * HID + n] : 0.0f;
            short hi, lo;
            split1(f, hi, lo);
            hd[j] = hi;
            ld[j] = lo;
        }
    } else if (idx < 1216 + 48640) {
        int i = idx - 1216;
        int n16 = i & 15; i >>= 4;
        int q = i & 3; i >>= 2;
        int nt = i % 19; i /= 19;
        int chunk = i % 10;
        int l = i / 10;
        int n = nt * 16 + n16;
        int cnt_idx = chunk * 19 + nt;
        short* base = wtl + (size_t)l * 194560;
        short* hd = base + (size_t)(cnt_idx * 8 + q) * 128 + n16 * 8;
        short* ld = base + (size_t)(cnt_idx * 8 + 4 + q) * 128 + n16 * 8;
#pragma unroll
        for (int j = 0; j < 8; ++j) {
            int k = chunk * 32 + q * 8 + j;
            float f = (k < HID && n < HID) ? gw[((size_t)l * HID + k) * HID + n] : 0.0f;
            short hi, lo;
            split1(f, hi, lo);
            hd[j] = hi;
            ld[j] = lo;
        }
    }
}

// k_scan: 1024 threads, 10 iterations (was 256x40 — 4x fewer serial steps)
__global__ __launch_bounds__(1024) void k_scan(
    const int* __restrict__ cnt, int* __restrict__ col_start,
    int* __restrict__ cursor, float* __restrict__ dinv,
    float* __restrict__ selfnorm) {
    __shared__ int wsum[16];
    int t = threadIdx.x;
    int lane = t & 63, w = t >> 6;
    int carry = 0;
    for (int base = 0; base < N_NODES; base += 1024) {
        int i = base + t;
        int v = (i < N_NODES) ? cnt[i] : 0;
        int s = v;
#pragma unroll
        for (int d = 1; d < 64; d <<= 1) {
            int n = __shfl_up(s, d, 64);
            if (lane >= d) s += n;
        }
        if (lane == 63) wsum[w] = s;
        __syncthreads();
        int woff = 0, total = 0;
#pragma unroll
        for (int k = 0; k < 16; ++k) {
            if (k < w) woff += wsum[k];
            total += wsum[k];
        }
        if (i < N_NODES) {
            int excl = carry + woff + s - v;
            col_start[i] = excl;
            cursor[i] = excl;
            float dd = (float)v + 1.0f;
            dinv[i] = rsqrtf(dd);
            selfnorm[i] = 1.0f / dd;
        }
        carry += total;
        __syncthreads();
    }
    if (t == 0) col_start[N_NODES] = carry;
}

// ---------------------------------------------------------------------------
// GCN core, MT 16-row tiles per wave, NTC n-tiles.
// Runtime chunk loop (unroll 1 — R5/R6 spill lesson), single-buffered,
// two B passes (hi then lo) sharing one A load.
// ---------------------------------------------------------------------------
template <int MT, int NTC>
__device__ __forceinline__ void kloop(const short* __restrict__ wp, int nch,
                                      const short* Hh, int nt0, int quad, int l16,
                                      f32x4 (&acc)[MT][NTC]) {
#pragma unroll
    for (int mt = 0; mt < MT; ++mt)
#pragma unroll
        for (int i = 0; i < NTC; ++i)
#pragma unroll
            for (int r = 0; r < 4; ++r) acc[mt][i][r] = 0.0f;
#pragma unroll 1
    for (int c = 0; c < nch; ++c) {
        const short* cb = wp + (size_t)(c * 19 + nt0) * 1024 + quad * 128 + l16 * 8;
        short8 ah[MT];
#pragma unroll
        for (int mt = 0; mt < MT; ++mt)
            ah[mt] = *(const short8*)&Hh[(mt * 16 + l16) * KS + c * 32 + quad * 8];
        short8 bb[NTC];
#pragma unroll
        for (int i = 0; i < NTC; ++i) bb[i] = *(const short8*)(cb + (size_t)i * 1024);
#pragma unroll
        for (int mt = 0; mt < MT; ++mt)
#pragma unroll
            for (int i = 0; i < NTC; ++i)
                acc[mt][i] = MFMA_B16(ah[mt], bb[i], acc[mt][i]);
#pragma unroll
        for (int i = 0; i < NTC; ++i) bb[i] = *(const short8*)(cb + (size_t)i * 1024 + 512);
#pragma unroll
        for (int mt = 0; mt < MT; ++mt)
#pragma unroll
            for (int i = 0; i < NTC; ++i)
                acc[mt][i] = MFMA_B16(ah[mt], bb[i], acc[mt][i]);
    }
}

template <int MT, int NTC>
__device__ __forceinline__ void gcn_epilogue(const float* __restrict__ bias,
                                             int nt0, int quad, int l16,
                                             f32x4 (&acc)[MT][NTC], short* Hh) {
#pragma unroll
    for (int i = 0; i < NTC; ++i) {
        int c = (nt0 + i) * 16 + l16;
        float b = (c < HID) ? bias[c] : 0.0f;
#pragma unroll
        for (int mt = 0; mt < MT; ++mt)
#pragma unroll
            for (int r = 0; r < 4; ++r) {
                float v = fmaxf(acc[mt][i][r] + b, 0.0f);
                Hh[(mt * 16 + quad * 4 + r) * KS + c] = bf16r(v);
            }
    }
}

// final layer of partB: masked column sums -> PLAIN coalesced store of
// per-block partials (replaces device atomics — the R9 82 MB HBM-RMW fix)
template <int MT, int NTC>
__device__ __forceinline__ void gcn_final(const float* __restrict__ bias,
                                          int nt0, int quad, int l16, int valid,
                                          f32x4 (&acc)[MT][NTC],
                                          float* __restrict__ gout) {
#pragma unroll
    for (int i = 0; i < NTC; ++i) {
        int c = (nt0 + i) * 16 + l16;
        float b = (c < HID) ? bias[c] : 0.0f;
        float s = 0.0f;
#pragma unroll
        for (int mt = 0; mt < MT; ++mt)
#pragma unroll
            for (int r = 0; r < 4; ++r) {
                int rr = mt * 16 + quad * 4 + r;
                float v = fmaxf(acc[mt][i][r] + b, 0.0f);
                if (rr < valid) s += v;
            }
        s += __shfl_xor(s, 16, 64);
        s += __shfl_xor(s, 32, 64);
        if (quad == 0) gout[c] = s;
    }
}

template <int MT, int NTC>
__device__ __forceinline__ void gemm_out(int base, int nt0, int quad, int l16,
                                         f32x4 (&acc)[MT][NTC],
                                         unsigned short* __restrict__ HW) {
#pragma unroll
    for (int i = 0; i < NTC; ++i) {
        int c = (nt0 + i) * 16 + l16;
#pragma unroll
        for (int mt = 0; mt < MT; ++mt)
#pragma unroll
            for (int r = 0; r < 4; ++r) {
                int gm = base + mt * 16 + quad * 4 + r;
                if (gm < N_NODES)
                    HW[(size_t)gm * HIDP + c] = (unsigned short)bf16r(acc[mt][i][r]);
            }
    }
}

// ---------------------------------------------------------------------------
// k_mega: partB (1563, 96 rows, 10 waves) U gemmA-L0 (105) U CSR-fill (250).
// 640 thr, launch_bounds(640,5): reg budget 102 (demand ~100), LDS 62976 B
// -> 2 blocks/CU = 20 waves/CU.
// ---------------------------------------------------------------------------
__global__ __launch_bounds__(640, 5) void k_mega(
    const float* __restrict__ edge_attr,
    const float* __restrict__ edge_w,
    const float* __restrict__ edge_b,
    const short* __restrict__ wt0,
    const short* __restrict__ wtl,
    const float* __restrict__ gcn0_b,
    const float* __restrict__ gcn_b,
    float* __restrict__ gpartB,      // [PARTB_BLOCKS][HIDP] plain partials
    unsigned short* __restrict__ hw0,
    const int* __restrict__ row,
    const int* __restrict__ col,
    int* __restrict__ cursor,
    const float* __restrict__ dinv,
    int2* __restrict__ edge_pack) {
    __shared__ short Hh[RBM * KS];   // 62976 B
    int bid = blockIdx.x, t = threadIdx.x;
    int lane = t & 63, w = t >> 6;          // 10 waves
    int l16 = lane & 15, quad = lane >> 4;
    int nt0 = w * 2;                         // waves 0..8: 2 n-tiles; wave 9: 1

    if (bid < PARTB_BLOCKS) {
        int base = N_NODES + bid * RBM;
        // inline edge embedding -> bf16 plane (96 x 32), zero invalid rows
        for (int i = t; i < RBM * 8; i += 640) {
            int r = i >> 3, c4 = (i & 7) * 4;
            int gr = base + r;
            float a0 = 0.f, a1 = 0.f, a2 = 0.f;
            bool ok = gr < N_EDGES;
            if (ok) {
                const float* ar = edge_attr + (size_t)gr * 3;
                a0 = ar[0]; a1 = ar[1]; a2 = ar[2];
            }
#pragma unroll
            for (int j = 0; j < 4; ++j) {
                int cc = c4 + j;
                float v = 0.0f;
                if (ok) {
                    v = edge_b[cc];
                    v = fmaf(a0, edge_w[cc], v);
                    v = fmaf(a1, edge_w[32 + cc], v);
                    v = fmaf(a2, edge_w[64 + cc], v);
                }
                Hh[r * KS + cc] = bf16r(v);
            }
        }
        for (int i = t; i < RBM * 24; i += 640) {
            int r = i / 24, k = 304 + i % 24;
            Hh[r * KS + k] = 0;
        }
        __syncthreads();

        int valid = N_EDGES - base;
        if (valid > RBM) valid = RBM;

        if (w < 9) {
            f32x4 acc[6][2];
            kloop<6, 2>(wt0, 1, Hh, nt0, quad, l16, acc);
            __syncthreads();
            gcn_epilogue<6, 2>(gcn0_b, nt0, quad, l16, acc, Hh);
            __syncthreads();
            for (int l = 0; l < 4; ++l) {
                const short* wp = wtl + (size_t)l * 194560;
                const float* bias = gcn_b + l * HID;
                kloop<6, 2>(wp, 10, Hh, nt0, quad, l16, acc);
                __syncthreads();
                if (l < 3) {
                    gcn_epilogue<6, 2>(bias, nt0, quad, l16, acc, Hh);
                    __syncthreads();
                } else {
                    gcn_final<6, 2>(bias, nt0, quad, l16, valid, acc,
                                    gpartB + (size_t)bid * HIDP);
                }
            }
        } else {
            f32x4 acc[6][1];
            kloop<6, 1>(wt0, 1, Hh, nt0, quad, l16, acc);
            __syncthreads();
            gcn_epilogue<6, 1>(gcn0_b, nt0, quad, l16, acc, Hh);
            __syncthreads();
            for (int l = 0; l < 4; ++l) {
                const short* wp = wtl + (size_t)l * 194560;
                const float* bias = gcn_b + l * HID;
                kloop<6, 1>(wp, 10, Hh, nt0, quad, l16, acc);
                __syncthreads();
                if (l < 3) {
                    gcn_epilogue<6, 1>(bias, nt0, quad, l16, acc, Hh);
                    __syncthreads();
                } else {
                    gcn_final<6, 1>(bias, nt0, quad, l16, valid, acc,
                                    gpartB + (size_t)bid * HIDP);
                }
            }
        }
    } else if (bid < PARTB_BLOCKS + GEMMA_BLOCKS) {
        // Part A layer-0 GEMM: hw0 = e @ W0
        int base = (bid - PARTB_BLOCKS) * RBM;
        for (int i = t; i < RBM * 8; i += 640) {
            int r = i >> 3, c4 = (i & 7) * 4;
            int gr = base + r;
            float a0 = 0.f, a1 = 0.f, a2 = 0.f;
            bool ok = gr < N_NODES;
            if (ok) {
                const float* ar = edge_attr + (size_t)gr * 3;
                a0 = ar[0]; a1 = ar[1]; a2 = ar[2];
            }
#pragma unroll
            for (int j = 0; j < 4; ++j) {
                int cc = c4 + j;
                float v = 0.0f;
                if (ok) {
                    v = edge_b[cc];
                    v = fmaf(a0, edge_w[cc], v);
                    v = fmaf(a1, edge_w[32 + cc], v);
                    v = fmaf(a2, edge_w[64 + cc], v);
                }
                Hh[r * KS + cc] = bf16r(v);
            }
        }
        for (int i = t; i < RBM * 24; i += 640) {
            int r = i / 24, k = 304 + i % 24;
            Hh[r * KS + k] = 0;
        }
        __syncthreads();
        if (w < 9) {
            f32x4 acc[6][2];
            kloop<6, 2>(wt0, 1, Hh, nt0, quad, l16, acc);
            gemm_out<6, 2>(base, nt0, quad, l16, acc, hw0);
        } else {
            f32x4 acc[6][1];
            kloop<6, 1>(wt0, 1, Hh, nt0, quad, l16, acc);
            gemm_out<6, 1>(base, nt0, quad, l16, acc, hw0);
        }
    } else {
        // CSR fill (row, norm)
        int e = (bid - PARTB_BLOCKS - GEMMA_BLOCKS) * 640 + t;
        if (e < N_EDGES) {
            int c = col[e], r = row[e];
            int p = atomicAdd(&cursor[c], 1);
            edge_pack[p] = make_int2(r, __float_as_int(dinv[r] * dinv[c]));
        }
    }
}

// ---------------------------------------------------------------------------
// agg of one node's neighbor sum into v[5] (R9-verified)
// ---------------------------------------------------------------------------
__device__ __forceinline__ void agg_row(int c, int lane,
                                        const unsigned short* __restrict__ hw_in,
                                        const int* __restrict__ col_start,
                                        const int2* __restrict__ edge_pack,
                                        float (&v)[5]) {
#pragma unroll
    for (int jj = 0; jj < 5; ++jj) v[jj] = 0.0f;
    int beg = col_start[c], end = col_start[c + 1];
    int i = beg;
    for (; i + 4 <= end; i += 4) {
        int2 e0 = edge_pack[i], e1 = edge_pack[i + 1];
        int2 e2 = edge_pack[i + 2], e3 = edge_pack[i + 3];
        const unsigned short* h0 = hw_in + (size_t)e0.x * HIDP;
        const unsigned short* h1 = hw_in + (size_t)e1.x * HIDP;
        const unsigned short* h2 = hw_in + (size_t)e2.x * HIDP;
        const unsigned short* h3 = hw_in + (size_t)e3.x * HIDP;
        float n0 = __int_as_float(e0.y), n1 = __int_as_float(e1.y);
        float n2 = __int_as_float(e2.y), n3 = __int_as_float(e3.y);
#pragma unroll
        for (int jj = 0; jj < 5; ++jj) {
            int cc = lane + 64 * jj;
            if (cc < HIDP) {
                float s = v[jj];
                s = fmaf(n0, b2f(h0[cc]), s);
                s = fmaf(n1, b2f(h1[cc]), s);
                s = fmaf(n2, b2f(h2[cc]), s);
                s = fmaf(n3, b2f(h3[cc]), s);
                v[jj] = s;
            }
        }
    }
    for (; i < end; ++i) {
        int2 e0 = edge_pack[i];
        const unsigned short* h0 = hw_in + (size_t)e0.x * HIDP;
        float n0 = __int_as_float(e0.y);
#pragma unroll
        for (int jj = 0; jj < 5; ++jj) {
            int cc = lane + 64 * jj;
            if (cc < HIDP) v[jj] = fmaf(n0, b2f(h0[cc]), v[jj]);
        }
    }
}

// ---------------------------------------------------------------------------
// k_fuse: agg(prev hw) -> relu+bias -> LDS -> gemm -> next hw (R9 structure)
// ---------------------------------------------------------------------------
__global__ __launch_bounds__(512, 6) void k_fuse(
    const unsigned short* __restrict__ hw_in,
    const int* __restrict__ col_start,
    const int2* __restrict__ edge_pack,
    const float* __restrict__ selfnorm,
    const float* __restrict__ bias,
    const short* __restrict__ wt,
    unsigned short* __restrict__ hw_out) {
    __shared__ short Hh[RBF * KS];
    int t = threadIdx.x;
    int lane = t & 63, w = t >> 6;
    int l16 = lane & 15, quad = lane >> 4;
    int base = blockIdx.x * RBF;
    int nt0 = (w < 3) ? w * 3 : 9 + (w - 3) * 2;

#pragma unroll 1
    for (int j = 0; j < 6; ++j) {
        int r = w * 6 + j;
        int c = base + r;
        if (c < N_NODES) {
            float v[5];
            agg_row(c, lane, hw_in, col_start, edge_pack, v);
            float sn = selfnorm[c];
            const unsigned short* sp = hw_in + (size_t)c * HIDP;
#pragma unroll
            for (int jj = 0; jj < 5; ++jj) {
                int cc = lane + 64 * jj;
                if (cc < HIDP) {
                    float h = v[jj] + sn * b2f(sp[cc]) + ((cc < HID) ? bias[cc] : 0.0f);
                    Hh[r * KS + cc] = bf16r(fmaxf(h, 0.0f));
                }
            }
        } else {
#pragma unroll
            for (int jj = 0; jj < 5; ++jj) {
                int cc = lane + 64 * jj;
                if (cc < HIDP) Hh[r * KS + cc] = 0;
            }
        }
    }
    for (int i = t; i < RBF * 24; i += 512) {
        int r = i / 24, k = 304 + i % 24;
        Hh[r * KS + k] = 0;
    }
    __syncthreads();

    if (w < 3) {
        f32x4 acc[3][3];
        kloop<3, 3>(wt, 10, Hh, nt0, quad, l16, acc);
        gemm_out<3, 3>(base, nt0, quad, l16, acc, hw_out);
    } else {
        f32x4 acc[3][2];
        kloop<3, 2>(wt, 10, Hh, nt0, quad, l16, acc);
        gemm_out<3, 2>(base, nt0, quad, l16, acc, hw_out);
    }
}

// ---------------------------------------------------------------------------
// k_last: final Part-A agg + column sums into g_sum (R9 structure)
// ---------------------------------------------------------------------------
__global__ __launch_bounds__(512) void k_last(
    const unsigned short* __restrict__ hw_in,
    const int* __restrict__ col_start,
    const int2* __restrict__ edge_pack,
    const float* __restrict__ selfnorm,
    const float* __restrict__ bias,
    float* __restrict__ g_sum) {
    __shared__ float red[8 * 320];
    int t = threadIdx.x;
    int lane = t & 63, w = t >> 6;
    int base = blockIdx.x * RBF;

    float s[5] = {0.0f, 0.0f, 0.0f, 0.0f, 0.0f};
#pragma unroll 1
    for (int j = 0; j < 6; ++j) {
        int c = base + w * 6 + j;
        if (c < N_NODES) {
            float v[5];
            agg_row(c, lane, hw_in, col_start, edge_pack, v);
            float sn = selfnorm[c];
            const unsigned short* sp = hw_in + (size_t)c * HIDP;
#pragma unroll
            for (int jj = 0; jj < 5; ++jj) {
                int cc = lane + 64 * jj;
                if (cc < HID) {
                    float h = v[jj] + sn * b2f(sp[cc]) + bias[cc];
                    s[jj] += fmaxf(h, 0.0f);
                }
            }
        }
    }
#pragma unroll
    for (int jj = 0; jj < 5; ++jj) red[w * 320 + lane + 64 * jj] = s[jj];
    __syncthreads();
    if (w == 0) {
#pragma unroll
        for (int jj = 0; jj < 5; ++jj) {
            int cc = lane + 64 * jj;
            if (cc < HID) {
                float tot = 0.0f;
#pragma unroll
                for (int g = 0; g < 8; ++g) tot += red[g * 320 + cc];
                atomicAdd(&g_sum[cc], tot);
            }
        }
    }
}

// k_gfold: reduce gpartB [1563][HIDP] -> g_sum (coalesced rows, few atomics)
__global__ void k_gfold(const float* __restrict__ gpartB, float* __restrict__ g_sum) {
    int b = blockIdx.x, t = threadIdx.x;
    int r0 = b * 16;
    int r1 = min(r0 + 16, PARTB_BLOCKS);
    float s0 = 0.0f, s1 = 0.0f;
    for (int r = r0; r < r1; ++r) {
        s0 += gpartB[(size_t)r * HIDP + t];
        if (t < HIDP - 256) s1 += gpartB[(size_t)r * HIDP + 256 + t];
    }
    if (t < HID) atomicAdd(&g_sum[t], s0);
    if (t < HIDP - 256 && 256 + t < HID) atomicAdd(&g_sum[256 + t], s1);
}

__global__ void k_head(const float* __restrict__ g_sum,
                       const float* __restrict__ lin1_w, const float* __restrict__ lin1_b,
                       const float* __restrict__ lin2_w, const float* __restrict__ lin2_b,
                       float* __restrict__ out) {
    __shared__ float g2[32];
    int t = threadIdx.x;
    const float inv = 1.0f / (float)N_EDGES;
    if (t < 32) {
        float a = lin1_b[t];
        for (int d = 0; d < HID; ++d) a = fmaf(g_sum[d] * inv, lin1_w[d * 32 + t], a);
        g2[t] = fmaxf(a, 0.0f);
    }
    __syncthreads();
    if (t < 2) {
        float p = lin2_b[t];
        for (int j = 0; j < 32; ++j) p = fmaf(g2[j], lin2_w[j * 2 + t], p);
        out[t] = p;
    }
}

// ---------------------------------------------------------------------------

extern "C" void kernel_launch(void* const* d_in, const int* in_sizes, int n_in,
                              void* d_out, int out_size, void* d_ws, size_t ws_size,
                              hipStream_t stream) {
    (void)in_sizes; (void)n_in; (void)out_size; (void)ws_size;
    const int* edge_index = (const int*)d_in[1];
    const float* edge_attr = (const float*)d_in[2];
    const float* edge_w = (const float*)d_in[6];
    const float* edge_b = (const float*)d_in[7];
    const float* gcn0_w = (const float*)d_in[8];
    const float* gcn0_b = (const float*)d_in[9];
    const float* gcn_w = (const float*)d_in[10];
    const float* gcn_b = (const float*)d_in[11];
    const float* lin1_w = (const float*)d_in[12];
    const float* lin1_b = (const float*)d_in[13];
    const float* lin2_w = (const float*)d_in[14];
    const float* lin2_b = (const float*)d_in[15];

    char* ws = (char*)d_ws;
    size_t off = 0;
    auto alloc = [&](size_t bytes) {
        void* p = ws + off;
        off = (off + bytes + 255) & ~(size_t)255;
        return p;
    };
    unsigned short* hwA = (unsigned short*)alloc((size_t)N_NODES * HIDP * 2);
    unsigned short* hwB = (unsigned short*)alloc((size_t)N_NODES * HIDP * 2);
    int2* edge_pack = (int2*)alloc((size_t)N_EDGES * 8);
    int* cnt = (int*)alloc((size_t)N_NODES * 4);
    int* col_start = (int*)alloc((size_t)(N_NODES + 1) * 4);
    int* cursor = (int*)alloc((size_t)N_NODES * 4);
    float* dinv = (float*)alloc((size_t)N_NODES * 4);
    float* selfnorm = (float*)alloc((size_t)N_NODES * 4);
    float* g_sum = (float*)alloc((size_t)HIDP * 4);
    short* wt0 = (short*)alloc((size_t)38912);
    short* wtl = (short*)alloc((size_t)4 * 389120);
    float* gpartB = (float*)alloc((size_t)PARTB_BLOCKS * HIDP * 4);

    const int* row = edge_index;
    const int* col = edge_index + N_EDGES;

    hipMemsetAsync(cnt, 0, N_NODES * 4, stream);
    hipMemsetAsync(g_sum, 0, HIDP * 4, stream);

    k_prep<<<(N_EDGES + 255) / 256, 256, 0, stream>>>(gcn0_w, gcn_w, wt0, wtl, col, cnt);
    k_scan<<<1, 1024, 0, stream>>>(cnt, col_start, cursor, dinv, selfnorm);

    // mega: partB (5 fused layers, 96-row blocks) + Part-A L0 gemm + CSR fill
    k_mega<<<MEGA_BLOCKS, 640, 0, stream>>>(edge_attr, edge_w, edge_b, wt0, wtl,
                                            gcn0_b, gcn_b, gpartB, hwA,
                                            row, col, cursor, dinv, edge_pack);

    // Part A layers 1..4: fused agg+gemm per layer
    k_fuse<<<FUSE_BLOCKS, 512, 0, stream>>>(hwA, col_start, edge_pack, selfnorm,
                                            gcn0_b, wtl + (size_t)0 * 194560, hwB);
    k_fuse<<<FUSE_BLOCKS, 512, 0, stream>>>(hwB, col_start, edge_pack, selfnorm,
                                            gcn_b + 0 * HID, wtl + (size_t)1 * 194560, hwA);
    k_fuse<<<FUSE_BLOCKS, 512, 0, stream>>>(hwA, col_start, edge_pack, selfnorm,
                                            gcn_b + 1 * HID, wtl + (size_t)2 * 194560, hwB);
    k_fuse<<<FUSE_BLOCKS, 512, 0, stream>>>(hwB, col_start, edge_pack, selfnorm,
                                            gcn_b + 2 * HID, wtl + (size_t)3 * 194560, hwA);
    // final agg + colsum (Part A), fold partB partials, head
    k_last<<<FUSE_BLOCKS, 512, 0, stream>>>(hwA, col_start, edge_pack, selfnorm,
                                            gcn_b + 3 * HID, g_sum);
    k_gfold<<<(PARTB_BLOCKS + 15) / 16, 256, 0, stream>>>(gpartB, g_sum);
    k_head<<<1, 64, 0, stream>>>(g_sum, lin1_w, lin1_b, lin2_w, lin2_b, (float*)d_out);
}

// Round 11
// 549.828 us; speedup vs baseline: 1.1589x; 1.0746x over previous
//
#include <hip/hip_runtime.h>
#include <hip/hip_bf16.h>

#define N_NODES 10000
#define N_EDGES 160000
#define HID 300
#define HIDP 304
#define NPARTB (N_EDGES - N_NODES)   // 150000
#define KS 328                        // H-plane k-stride in shorts
#define RB 48                         // mega rows/block (3 M-tiles); exact 3125
#define RBF 32                        // fuse rows/block (2 M-tiles)
#define PARTB_BLOCKS 3125             // 150000/48 exact
#define GEMMA_BLOCKS 209              // ceil(10000/48)
#define FILL_BLOCKS 313               // ceil(160000/512)
#define MEGA_BLOCKS (PARTB_BLOCKS + GEMMA_BLOCKS + FILL_BLOCKS)
#define FUSE_BLOCKS 313               // ceil(10000/32)

typedef __attribute__((ext_vector_type(8))) short short8;
typedef __attribute__((ext_vector_type(4))) float f32x4;

#define MFMA_B16(a, b, c) __builtin_amdgcn_mfma_f32_16x16x32_bf16(a, b, c, 0, 0, 0)

__device__ __forceinline__ short bf16r(float x) {
    unsigned u = __float_as_uint(x);
    return (short)((u + 0x7fffu + ((u >> 16) & 1u)) >> 16);
}
__device__ __forceinline__ float b2f(unsigned short u) {
    return __uint_as_float(((unsigned)u) << 16);
}
__device__ __forceinline__ void split1(float x, short& hi, short& lo) {
    short h = bf16r(x);
    float hf = __uint_as_float(((unsigned)(unsigned short)h) << 16);
    hi = h;
    lo = bf16r(x - hf);
}

// ---------------------------------------------------------------------------
// k_prep: weight pre-split (layout verified R2-R10) + degree count.
// ---------------------------------------------------------------------------
__global__ void k_prep(const float* __restrict__ g0w, const float* __restrict__ gw,
                       short* __restrict__ wt0, short* __restrict__ wtl,
                       const int* __restrict__ col, int* __restrict__ cnt) {
    int idx = blockIdx.x * 256 + threadIdx.x;
    if (idx < N_EDGES) atomicAdd(&cnt[col[idx]], 1);
    if (idx < 1216) {
        int n16 = idx & 15, q = (idx >> 4) & 3, nt = idx >> 6;
        int n = nt * 16 + n16;
        short* hd = wt0 + (size_t)(nt * 8 + q) * 128 + n16 * 8;
        short* ld = wt0 + (size_t)(nt * 8 + 4 + q) * 128 + n16 * 8;
#pragma unroll
        for (int j = 0; j < 8; ++j) {
            int k = q * 8 + j;
            float f = (n < HID) ? g0w[k * HID + n] : 0.0f;
            short hi, lo;
            split1(f, hi, lo);
            hd[j] = hi;
            ld[j] = lo;
        }
    } else if (idx < 1216 + 48640) {
        int i = idx - 1216;
        int n16 = i & 15; i >>= 4;
        int q = i & 3; i >>= 2;
        int nt = i % 19; i /= 19;
        int chunk = i % 10;
        int l = i / 10;
        int n = nt * 16 + n16;
        int cnt_idx = chunk * 19 + nt;
        short* base = wtl + (size_t)l * 194560;
        short* hd = base + (size_t)(cnt_idx * 8 + q) * 128 + n16 * 8;
        short* ld = base + (size_t)(cnt_idx * 8 + 4 + q) * 128 + n16 * 8;
#pragma unroll
        for (int j = 0; j < 8; ++j) {
            int k = chunk * 32 + q * 8 + j;
            float f = (k < HID && n < HID) ? gw[((size_t)l * HID + k) * HID + n] : 0.0f;
            short hi, lo;
            split1(f, hi, lo);
            hd[j] = hi;
            ld[j] = lo;
        }
    }
}

// k_scan: 1024 threads, 10 iterations (R10-verified)
__global__ __launch_bounds__(1024) void k_scan(
    const int* __restrict__ cnt, int* __restrict__ col_start,
    int* __restrict__ cursor, float* __restrict__ dinv,
    float* __restrict__ selfnorm) {
    __shared__ int wsum[16];
    int t = threadIdx.x;
    int lane = t & 63, w = t >> 6;
    int carry = 0;
    for (int base = 0; base < N_NODES; base += 1024) {
        int i = base + t;
        int v = (i < N_NODES) ? cnt[i] : 0;
        int s = v;
#pragma unroll
        for (int d = 1; d < 64; d <<= 1) {
            int n = __shfl_up(s, d, 64);
            if (lane >= d) s += n;
        }
        if (lane == 63) wsum[w] = s;
        __syncthreads();
        int woff = 0, total = 0;
#pragma unroll
        for (int k = 0; k < 16; ++k) {
            if (k < w) woff += wsum[k];
            total += wsum[k];
        }
        if (i < N_NODES) {
            int excl = carry + woff + s - v;
            col_start[i] = excl;
            cursor[i] = excl;
            float dd = (float)v + 1.0f;
            dinv[i] = rsqrtf(dd);
            selfnorm[i] = 1.0f / dd;
        }
        carry += total;
        __syncthreads();
    }
    if (t == 0) col_start[N_NODES] = carry;
}

// ---------------------------------------------------------------------------
// GCN core (R9/R10-verified): MT 16-row tiles/wave, NTC n-tiles, 2-term
// split-bf16, runtime chunk loop (unroll 1 — spill lesson), single-buffered.
// ---------------------------------------------------------------------------
template <int MT, int NTC>
__device__ __forceinline__ void kloop(const short* __restrict__ wp, int nch,
                                      const short* Hh, int nt0, int quad, int l16,
                                      f32x4 (&acc)[MT][NTC]) {
#pragma unroll
    for (int mt = 0; mt < MT; ++mt)
#pragma unroll
        for (int i = 0; i < NTC; ++i)
#pragma unroll
            for (int r = 0; r < 4; ++r) acc[mt][i][r] = 0.0f;
#pragma unroll 1
    for (int c = 0; c < nch; ++c) {
        const short* cb = wp + (size_t)(c * 19 + nt0) * 1024 + quad * 128 + l16 * 8;
        short8 ah[MT];
#pragma unroll
        for (int mt = 0; mt < MT; ++mt)
            ah[mt] = *(const short8*)&Hh[(mt * 16 + l16) * KS + c * 32 + quad * 8];
        short8 bb[NTC];
#pragma unroll
        for (int i = 0; i < NTC; ++i) bb[i] = *(const short8*)(cb + (size_t)i * 1024);
#pragma unroll
        for (int mt = 0; mt < MT; ++mt)
#pragma unroll
            for (int i = 0; i < NTC; ++i)
                acc[mt][i] = MFMA_B16(ah[mt], bb[i], acc[mt][i]);
#pragma unroll
        for (int i = 0; i < NTC; ++i) bb[i] = *(const short8*)(cb + (size_t)i * 1024 + 512);
#pragma unroll
        for (int mt = 0; mt < MT; ++mt)
#pragma unroll
            for (int i = 0; i < NTC; ++i)
                acc[mt][i] = MFMA_B16(ah[mt], bb[i], acc[mt][i]);
    }
}

template <int MT, int NTC>
__device__ __forceinline__ void gcn_epilogue(const float* __restrict__ bias,
                                             int nt0, int quad, int l16,
                                             f32x4 (&acc)[MT][NTC], short* Hh) {
#pragma unroll
    for (int i = 0; i < NTC; ++i) {
        int c = (nt0 + i) * 16 + l16;
        float b = (c < HID) ? bias[c] : 0.0f;
#pragma unroll
        for (int mt = 0; mt < MT; ++mt)
#pragma unroll
            for (int r = 0; r < 4; ++r) {
                float v = fmaxf(acc[mt][i][r] + b, 0.0f);
                Hh[(mt * 16 + quad * 4 + r) * KS + c] = bf16r(v);
            }
    }
}

// final partB layer: column sums -> PLAIN per-block store (R10 fix; zero-fill
// cols >= HID so the fold kernel reads clean data)
template <int MT, int NTC>
__device__ __forceinline__ void gcn_final(const float* __restrict__ bias,
                                          int nt0, int quad, int l16,
                                          f32x4 (&acc)[MT][NTC],
                                          float* __restrict__ gout) {
#pragma unroll
    for (int i = 0; i < NTC; ++i) {
        int c = (nt0 + i) * 16 + l16;
        float b = (c < HID) ? bias[c] : 0.0f;
        float s = 0.0f;
#pragma unroll
        for (int mt = 0; mt < MT; ++mt)
#pragma unroll
            for (int r = 0; r < 4; ++r) s += fmaxf(acc[mt][i][r] + b, 0.0f);
        s += __shfl_xor(s, 16, 64);
        s += __shfl_xor(s, 32, 64);
        if (quad == 0) gout[c] = (c < HID) ? s : 0.0f;
    }
}

template <int MT, int NTC>
__device__ __forceinline__ void gemm_out(int base, int nt0, int quad, int l16,
                                         f32x4 (&acc)[MT][NTC],
                                         unsigned short* __restrict__ HW) {
#pragma unroll
    for (int i = 0; i < NTC; ++i) {
        int c = (nt0 + i) * 16 + l16;
#pragma unroll
        for (int mt = 0; mt < MT; ++mt)
#pragma unroll
            for (int r = 0; r < 4; ++r) {
                int gm = base + mt * 16 + quad * 4 + r;
                if (gm < N_NODES)
                    HW[(size_t)gm * HIDP + c] = (unsigned short)bf16r(acc[mt][i][r]);
            }
    }
}

// ---------------------------------------------------------------------------
// k_mega: partB (3125, 48 rows, 8 waves) U gemmA-L0 (209) U CSR-fill (313).
// (512,6): reg budget 85 (demand ~75, R9 measured VGPR 40 no-spill);
// LDS 31488 B -> 3 blocks/CU = 24 waves/CU.
// ---------------------------------------------------------------------------
__global__ __launch_bounds__(512, 6) void k_mega(
    const float* __restrict__ edge_attr,
    const float* __restrict__ edge_w,
    const float* __restrict__ edge_b,
    const short* __restrict__ wt0,
    const short* __restrict__ wtl,
    const float* __restrict__ gcn0_b,
    const float* __restrict__ gcn_b,
    float* __restrict__ gpartB,      // [PARTB_BLOCKS][HIDP] plain partials
    unsigned short* __restrict__ hw0,
    const int* __restrict__ row,
    const int* __restrict__ col,
    int* __restrict__ cursor,
    const float* __restrict__ dinv,
    int2* __restrict__ edge_pack) {
    __shared__ short Hh[RB * KS];   // 31488 B
    int bid = blockIdx.x, t = threadIdx.x;
    int lane = t & 63, w = t >> 6;
    int l16 = lane & 15, quad = lane >> 4;
    int nt0 = (w < 3) ? w * 3 : 9 + (w - 3) * 2;

    if (bid < PARTB_BLOCKS) {
        // ---------------- Part B unit (fused 5-layer) ----------------
        int base = N_NODES + bid * RB;   // exact, no row masking needed
        if (t < 384) {
            int r = t >> 3, c4 = (t & 7) * 4;
            const float* ar = edge_attr + (size_t)(base + r) * 3;
            float a0 = ar[0], a1 = ar[1], a2 = ar[2];
#pragma unroll
            for (int j = 0; j < 4; ++j) {
                int cc = c4 + j;
                float v = edge_b[cc];
                v = fmaf(a0, edge_w[cc], v);
                v = fmaf(a1, edge_w[32 + cc], v);
                v = fmaf(a2, edge_w[64 + cc], v);
                Hh[r * KS + cc] = bf16r(v);
            }
        }
        for (int i = t; i < RB * 24; i += 512) {
            int r = i / 24, k = 304 + i % 24;
            Hh[r * KS + k] = 0;
        }
        __syncthreads();

        float* gout = gpartB + (size_t)bid * HIDP;
        if (w < 3) {
            f32x4 acc[3][3];
            kloop<3, 3>(wt0, 1, Hh, nt0, quad, l16, acc);
            __syncthreads();
            gcn_epilogue<3, 3>(gcn0_b, nt0, quad, l16, acc, Hh);
            __syncthreads();
            for (int l = 0; l < 4; ++l) {
                kloop<3, 3>(wtl + (size_t)l * 194560, 10, Hh, nt0, quad, l16, acc);
                __syncthreads();
                if (l < 3) {
                    gcn_epilogue<3, 3>(gcn_b + l * HID, nt0, quad, l16, acc, Hh);
                    __syncthreads();
                } else {
                    gcn_final<3, 3>(gcn_b + l * HID, nt0, quad, l16, acc, gout);
                }
            }
        } else {
            f32x4 acc[3][2];
            kloop<3, 2>(wt0, 1, Hh, nt0, quad, l16, acc);
            __syncthreads();
            gcn_epilogue<3, 2>(gcn0_b, nt0, quad, l16, acc, Hh);
            __syncthreads();
            for (int l = 0; l < 4; ++l) {
                kloop<3, 2>(wtl + (size_t)l * 194560, 10, Hh, nt0, quad, l16, acc);
                __syncthreads();
                if (l < 3) {
                    gcn_epilogue<3, 2>(gcn_b + l * HID, nt0, quad, l16, acc, Hh);
                    __syncthreads();
                } else {
                    gcn_final<3, 2>(gcn_b + l * HID, nt0, quad, l16, acc, gout);
                }
            }
        }
    } else if (bid < PARTB_BLOCKS + GEMMA_BLOCKS) {
        // ---------------- Part A layer-0 GEMM ----------------
        int base = (bid - PARTB_BLOCKS) * RB;
        if (t < 384) {
            int r = t >> 3, c4 = (t & 7) * 4;
            int gr = base + r;
            float a0 = 0.f, a1 = 0.f, a2 = 0.f;
            bool ok = gr < N_NODES;
            if (ok) {
                const float* ar = edge_attr + (size_t)gr * 3;
                a0 = ar[0]; a1 = ar[1]; a2 = ar[2];
            }
#pragma unroll
            for (int j = 0; j < 4; ++j) {
                int cc = c4 + j;
                float v = 0.0f;
                if (ok) {
                    v = edge_b[cc];
                    v = fmaf(a0, edge_w[cc], v);
                    v = fmaf(a1, edge_w[32 + cc], v);
                    v = fmaf(a2, edge_w[64 + cc], v);
                }
                Hh[r * KS + cc] = bf16r(v);
            }
        }
        for (int i = t; i < RB * 24; i += 512) {
            int r = i / 24, k = 304 + i % 24;
            Hh[r * KS + k] = 0;
        }
        __syncthreads();
        if (w < 3) {
            f32x4 acc[3][3];
            kloop<3, 3>(wt0, 1, Hh, nt0, quad, l16, acc);
            gemm_out<3, 3>(base, nt0, quad, l16, acc, hw0);
        } else {
            f32x4 acc[3][2];
            kloop<3, 2>(wt0, 1, Hh, nt0, quad, l16, acc);
            gemm_out<3, 2>(base, nt0, quad, l16, acc, hw0);
        }
    } else {
        // ---------------- CSR fill (row, norm) ----------------
        int e = (bid - PARTB_BLOCKS - GEMMA_BLOCKS) * 512 + t;
        if (e < N_EDGES) {
            int c = col[e], r = row[e];
            int p = atomicAdd(&cursor[c], 1);
            edge_pack[p] = make_int2(r, __float_as_int(dinv[r] * dinv[c]));
        }
    }
}

// ---------------------------------------------------------------------------
// agg of one node's neighbor sum into v[5] (R9/R10-verified)
// ---------------------------------------------------------------------------
__device__ __forceinline__ void agg_row(int c, int lane,
                                        const unsigned short* __restrict__ hw_in,
                                        const int* __restrict__ col_start,
                                        const int2* __restrict__ edge_pack,
                                        float (&v)[5]) {
#pragma unroll
    for (int jj = 0; jj < 5; ++jj) v[jj] = 0.0f;
    int beg = col_start[c], end = col_start[c + 1];
    int i = beg;
    for (; i + 4 <= end; i += 4) {
        int2 e0 = edge_pack[i], e1 = edge_pack[i + 1];
        int2 e2 = edge_pack[i + 2], e3 = edge_pack[i + 3];
        const unsigned short* h0 = hw_in + (size_t)e0.x * HIDP;
        const unsigned short* h1 = hw_in + (size_t)e1.x * HIDP;
        const unsigned short* h2 = hw_in + (size_t)e2.x * HIDP;
        const unsigned short* h3 = hw_in + (size_t)e3.x * HIDP;
        float n0 = __int_as_float(e0.y), n1 = __int_as_float(e1.y);
        float n2 = __int_as_float(e2.y), n3 = __int_as_float(e3.y);
#pragma unroll
        for (int jj = 0; jj < 5; ++jj) {
            int cc = lane + 64 * jj;
            if (cc < HIDP) {
                float s = v[jj];
                s = fmaf(n0, b2f(h0[cc]), s);
                s = fmaf(n1, b2f(h1[cc]), s);
                s = fmaf(n2, b2f(h2[cc]), s);
                s = fmaf(n3, b2f(h3[cc]), s);
                v[jj] = s;
            }
        }
    }
    for (; i < end; ++i) {
        int2 e0 = edge_pack[i];
        const unsigned short* h0 = hw_in + (size_t)e0.x * HIDP;
        float n0 = __int_as_float(e0.y);
#pragma unroll
        for (int jj = 0; jj < 5; ++jj) {
            int cc = lane + 64 * jj;
            if (cc < HIDP) v[jj] = fmaf(n0, b2f(h0[cc]), v[jj]);
        }
    }
}

// ---------------------------------------------------------------------------
// k_fuse: agg(prev hw) -> relu+bias -> LDS -> gemm -> next hw.
// RBF=32 (2 M-tiles): 313 blocks (> 256 CUs), 20992 B LDS, (512,6).
// ---------------------------------------------------------------------------
__global__ __launch_bounds__(512, 6) void k_fuse(
    const unsigned short* __restrict__ hw_in,
    const int* __restrict__ col_start,
    const int2* __restrict__ edge_pack,
    const float* __restrict__ selfnorm,
    const float* __restrict__ bias,
    const short* __restrict__ wt,
    unsigned short* __restrict__ hw_out) {
    __shared__ short Hh[RBF * KS];
    int t = threadIdx.x;
    int lane = t & 63, w = t >> 6;
    int l16 = lane & 15, quad = lane >> 4;
    int base = blockIdx.x * RBF;
    int nt0 = (w < 3) ? w * 3 : 9 + (w - 3) * 2;

#pragma unroll 1
    for (int j = 0; j < 4; ++j) {
        int r = w * 4 + j;
        int c = base + r;
        if (c < N_NODES) {
            float v[5];
            agg_row(c, lane, hw_in, col_start, edge_pack, v);
            float sn = selfnorm[c];
            const unsigned short* sp = hw_in + (size_t)c * HIDP;
#pragma unroll
            for (int jj = 0; jj < 5; ++jj) {
                int cc = lane + 64 * jj;
                if (cc < HIDP) {
                    float h = v[jj] + sn * b2f(sp[cc]) + ((cc < HID) ? bias[cc] : 0.0f);
                    Hh[r * KS + cc] = bf16r(fmaxf(h, 0.0f));
                }
            }
        } else {
#pragma unroll
            for (int jj = 0; jj < 5; ++jj) {
                int cc = lane + 64 * jj;
                if (cc < HIDP) Hh[r * KS + cc] = 0;
            }
        }
    }
    for (int i = t; i < RBF * 24; i += 512) {
        int r = i / 24, k = 304 + i % 24;
        Hh[r * KS + k] = 0;
    }
    __syncthreads();

    if (w < 3) {
        f32x4 acc[2][3];
        kloop<2, 3>(wt, 10, Hh, nt0, quad, l16, acc);
        gemm_out<2, 3>(base, nt0, quad, l16, acc, hw_out);
    } else {
        f32x4 acc[2][2];
        kloop<2, 2>(wt, 10, Hh, nt0, quad, l16, acc);
        gemm_out<2, 2>(base, nt0, quad, l16, acc, hw_out);
    }
}

// ---------------------------------------------------------------------------
// k_last: final Part-A agg + column sums into g_sum. RBF=32, 313 blocks.
// ---------------------------------------------------------------------------
__global__ __launch_bounds__(512) void k_last(
    const unsigned short* __restrict__ hw_in,
    const int* __restrict__ col_start,
    const int2* __restrict__ edge_pack,
    const float* __restrict__ selfnorm,
    const float* __restrict__ bias,
    float* __restrict__ g_sum) {
    __shared__ float red[8 * 320];
    int t = threadIdx.x;
    int lane = t & 63, w = t >> 6;
    int base = blockIdx.x * RBF;

    float s[5] = {0.0f, 0.0f, 0.0f, 0.0f, 0.0f};
#pragma unroll 1
    for (int j = 0; j < 4; ++j) {
        int c = base + w * 4 + j;
        if (c < N_NODES) {
            float v[5];
            agg_row(c, lane, hw_in, col_start, edge_pack, v);
            float sn = selfnorm[c];
            const unsigned short* sp = hw_in + (size_t)c * HIDP;
#pragma unroll
            for (int jj = 0; jj < 5; ++jj) {
                int cc = lane + 64 * jj;
                if (cc < HID) {
                    float h = v[jj] + sn * b2f(sp[cc]) + bias[cc];
                    s[jj] += fmaxf(h, 0.0f);
                }
            }
        }
    }
#pragma unroll
    for (int jj = 0; jj < 5; ++jj) red[w * 320 + lane + 64 * jj] = s[jj];
    __syncthreads();
    if (w == 0) {
#pragma unroll
        for (int jj = 0; jj < 5; ++jj) {
            int cc = lane + 64 * jj;
            if (cc < HID) {
                float tot = 0.0f;
#pragma unroll
                for (int g = 0; g < 8; ++g) tot += red[g * 320 + cc];
                atomicAdd(&g_sum[cc], tot);
            }
        }
    }
}

// k_gfold: reduce gpartB [3125][HIDP] -> g_sum (coalesced, few atomics)
__global__ void k_gfold(const float* __restrict__ gpartB, float* __restrict__ g_sum) {
    int b = blockIdx.x, t = threadIdx.x;
    int r0 = b * 32;
    int r1 = min(r0 + 32, PARTB_BLOCKS);
    float s0 = 0.0f, s1 = 0.0f;
    for (int r = r0; r < r1; ++r) {
        s0 += gpartB[(size_t)r * HIDP + t];
        if (t < HIDP - 256) s1 += gpartB[(size_t)r * HIDP + 256 + t];
    }
    if (t < HID) atomicAdd(&g_sum[t], s0);
    if (t < HIDP - 256 && 256 + t < HID) atomicAdd(&g_sum[256 + t], s1);
}

__global__ void k_head(const float* __restrict__ g_sum,
                       const float* __restrict__ lin1_w, const float* __restrict__ lin1_b,
                       const float* __restrict__ lin2_w, const float* __restrict__ lin2_b,
                       float* __restrict__ out) {
    __shared__ float g2[32];
    int t = threadIdx.x;
    const float inv = 1.0f / (float)N_EDGES;
    if (t < 32) {
        float a = lin1_b[t];
        for (int d = 0; d < HID; ++d) a = fmaf(g_sum[d] * inv, lin1_w[d * 32 + t], a);
        g2[t] = fmaxf(a, 0.0f);
    }
    __syncthreads();
    if (t < 2) {
        float p = lin2_b[t];
        for (int j = 0; j < 32; ++j) p = fmaf(g2[j], lin2_w[j * 2 + t], p);
        out[t] = p;
    }
}

// ---------------------------------------------------------------------------

extern "C" void kernel_launch(void* const* d_in, const int* in_sizes, int n_in,
                              void* d_out, int out_size, void* d_ws, size_t ws_size,
                              hipStream_t stream) {
    (void)in_sizes; (void)n_in; (void)out_size; (void)ws_size;
    const int* edge_index = (const int*)d_in[1];
    const float* edge_attr = (const float*)d_in[2];
    const float* edge_w = (const float*)d_in[6];
    const float* edge_b = (const float*)d_in[7];
    const float* gcn0_w = (const float*)d_in[8];
    const float* gcn0_b = (const float*)d_in[9];
    const float* gcn_w = (const float*)d_in[10];
    const float* gcn_b = (const float*)d_in[11];
    const float* lin1_w = (const float*)d_in[12];
    const float* lin1_b = (const float*)d_in[13];
    const float* lin2_w = (const float*)d_in[14];
    const float* lin2_b = (const float*)d_in[15];

    char* ws = (char*)d_ws;
    size_t off = 0;
    auto alloc = [&](size_t bytes) {
        void* p = ws + off;
        off = (off + bytes + 255) & ~(size_t)255;
        return p;
    };
    unsigned short* hwA = (unsigned short*)alloc((size_t)N_NODES * HIDP * 2);
    unsigned short* hwB = (unsigned short*)alloc((size_t)N_NODES * HIDP * 2);
    int2* edge_pack = (int2*)alloc((size_t)N_EDGES * 8);
    int* cnt = (int*)alloc((size_t)N_NODES * 4);
    int* col_start = (int*)alloc((size_t)(N_NODES + 1) * 4);
    int* cursor = (int*)alloc((size_t)N_NODES * 4);
    float* dinv = (float*)alloc((size_t)N_NODES * 4);
    float* selfnorm = (float*)alloc((size_t)N_NODES * 4);
    float* g_sum = (float*)alloc((size_t)HIDP * 4);
    short* wt0 = (short*)alloc((size_t)38912);
    short* wtl = (short*)alloc((size_t)4 * 389120);
    float* gpartB = (float*)alloc((size_t)PARTB_BLOCKS * HIDP * 4);

    const int* row = edge_index;
    const int* col = edge_index + N_EDGES;

    hipMemsetAsync(cnt, 0, N_NODES * 4, stream);
    hipMemsetAsync(g_sum, 0, HIDP * 4, stream);

    k_prep<<<(N_EDGES + 255) / 256, 256, 0, stream>>>(gcn0_w, gcn_w, wt0, wtl, col, cnt);
    k_scan<<<1, 1024, 0, stream>>>(cnt, col_start, cursor, dinv, selfnorm);

    // mega: partB (R9 shape + R10 plain stores) + Part-A L0 gemm + CSR fill
    k_mega<<<MEGA_BLOCKS, 512, 0, stream>>>(edge_attr, edge_w, edge_b, wt0, wtl,
                                            gcn0_b, gcn_b, gpartB, hwA,
                                            row, col, cursor, dinv, edge_pack);

    // Part A layers 1..4: fused agg+gemm per layer (313 blocks each)
    k_fuse<<<FUSE_BLOCKS, 512, 0, stream>>>(hwA, col_start, edge_pack, selfnorm,
                                            gcn0_b, wtl + (size_t)0 * 194560, hwB);
    k_fuse<<<FUSE_BLOCKS, 512, 0, stream>>>(hwB, col_start, edge_pack, selfnorm,
                                            gcn_b + 0 * HID, wtl + (size_t)1 * 194560, hwA);
    k_fuse<<<FUSE_BLOCKS, 512, 0, stream>>>(hwA, col_start, edge_pack, selfnorm,
                                            gcn_b + 1 * HID, wtl + (size_t)2 * 194560, hwB);
    k_fuse<<<FUSE_BLOCKS, 512, 0, stream>>>(hwB, col_start, edge_pack, selfnorm,
                                            gcn_b + 2 * HID, wtl + (size_t)3 * 194560, hwA);
    // final agg + colsum (Part A), fold partB partials, head
    k_last<<<FUSE_BLOCKS, 512, 0, stream>>>(hwA, col_start, edge_pack, selfnorm,
                                            gcn_b + 3 * HID, g_sum);
    k_gfold<<<(PARTB_BLOCKS + 31) / 32, 256, 0, stream>>>(gpartB, g_sum);
    k_head<<<1, 64, 0, stream>>>(g_sum, lin1_w, lin1_b, lin2_w, lin2_b, (float*)d_out);
}

// Round 12
// 465.527 us; speedup vs baseline: 1.3688x; 1.1811x over previous
//
#include <hip/hip_runtime.h>
#include <hip/hip_bf16.h>

#define N_NODES 10000
#define N_EDGES 160000
#define HID 300
#define HIDP 304
#define NPARTB (N_EDGES - N_NODES)   // 150000
#define KS 328                        // H-plane k-stride in shorts
#define RBM 80                        // mega rows/block (5 M-tiles); exact 1875
#define RBF 32                        // fuse rows/block (2 M-tiles)
#define PARTB_BLOCKS 1875             // 150000/80 exact
#define GEMMA_BLOCKS 125              // 10000/80 exact
#define FILL_BLOCKS 313               // ceil(160000/512)
#define MEGA_BLOCKS (PARTB_BLOCKS + GEMMA_BLOCKS + FILL_BLOCKS)
#define FUSE_BLOCKS 313               // ceil(10000/32)

typedef __attribute__((ext_vector_type(8))) short short8;
typedef __attribute__((ext_vector_type(4))) float f32x4;

#define MFMA_B16(a, b, c) __builtin_amdgcn_mfma_f32_16x16x32_bf16(a, b, c, 0, 0, 0)

__device__ __forceinline__ short bf16r(float x) {
    unsigned u = __float_as_uint(x);
    return (short)((u + 0x7fffu + ((u >> 16) & 1u)) >> 16);
}
__device__ __forceinline__ float b2f(unsigned short u) {
    return __uint_as_float(((unsigned)u) << 16);
}
__device__ __forceinline__ void split1(float x, short& hi, short& lo) {
    short h = bf16r(x);
    float hf = __uint_as_float(((unsigned)(unsigned short)h) << 16);
    hi = h;
    lo = bf16r(x - hf);
}

// ---------------------------------------------------------------------------
// k_prep: weight pre-split (layout verified R2-R11) + degree count.
// ---------------------------------------------------------------------------
__global__ void k_prep(const float* __restrict__ g0w, const float* __restrict__ gw,
                       short* __restrict__ wt0, short* __restrict__ wtl,
                       const int* __restrict__ col, int* __restrict__ cnt) {
    int idx = blockIdx.x * 256 + threadIdx.x;
    if (idx < N_EDGES) atomicAdd(&cnt[col[idx]], 1);
    if (idx < 1216) {
        int n16 = idx & 15, q = (idx >> 4) & 3, nt = idx >> 6;
        int n = nt * 16 + n16;
        short* hd = wt0 + (size_t)(nt * 8 + q) * 128 + n16 * 8;
        short* ld = wt0 + (size_t)(nt * 8 + 4 + q) * 128 + n16 * 8;
#pragma unroll
        for (int j = 0; j < 8; ++j) {
            int k = q * 8 + j;
            float f = (n < HID) ? g0w[k * HID + n] : 0.0f;
            short hi, lo;
            split1(f, hi, lo);
            hd[j] = hi;
            ld[j] = lo;
        }
    } else if (idx < 1216 + 48640) {
        int i = idx - 1216;
        int n16 = i & 15; i >>= 4;
        int q = i & 3; i >>= 2;
        int nt = i % 19; i /= 19;
        int chunk = i % 10;
        int l = i / 10;
        int n = nt * 16 + n16;
        int cnt_idx = chunk * 19 + nt;
        short* base = wtl + (size_t)l * 194560;
        short* hd = base + (size_t)(cnt_idx * 8 + q) * 128 + n16 * 8;
        short* ld = base + (size_t)(cnt_idx * 8 + 4 + q) * 128 + n16 * 8;
#pragma unroll
        for (int j = 0; j < 8; ++j) {
            int k = chunk * 32 + q * 8 + j;
            float f = (k < HID && n < HID) ? gw[((size_t)l * HID + k) * HID + n] : 0.0f;
            short hi, lo;
            split1(f, hi, lo);
            hd[j] = hi;
            ld[j] = lo;
        }
    }
}

// k_scan: 1024 threads, 10 iterations (R10/R11-verified)
__global__ __launch_bounds__(1024) void k_scan(
    const int* __restrict__ cnt, int* __restrict__ col_start,
    int* __restrict__ cursor, float* __restrict__ dinv,
    float* __restrict__ selfnorm) {
    __shared__ int wsum[16];
    int t = threadIdx.x;
    int lane = t & 63, w = t >> 6;
    int carry = 0;
    for (int base = 0; base < N_NODES; base += 1024) {
        int i = base + t;
        int v = (i < N_NODES) ? cnt[i] : 0;
        int s = v;
#pragma unroll
        for (int d = 1; d < 64; d <<= 1) {
            int n = __shfl_up(s, d, 64);
            if (lane >= d) s += n;
        }
        if (lane == 63) wsum[w] = s;
        __syncthreads();
        int woff = 0, total = 0;
#pragma unroll
        for (int k = 0; k < 16; ++k) {
            if (k < w) woff += wsum[k];
            total += wsum[k];
        }
        if (i < N_NODES) {
            int excl = carry + woff + s - v;
            col_start[i] = excl;
            cursor[i] = excl;
            float dd = (float)v + 1.0f;
            dinv[i] = rsqrtf(dd);
            selfnorm[i] = 1.0f / dd;
        }
        carry += total;
        __syncthreads();
    }
    if (t == 0) col_start[N_NODES] = carry;
}

// ---------------------------------------------------------------------------
// GCN core (verified R9-R11): MT 16-row tiles/wave, NTC n-tiles, 2-term
// split-bf16, runtime chunk loop (unroll 1 — spill lesson), single-buffered.
// ---------------------------------------------------------------------------
template <int MT, int NTC>
__device__ __forceinline__ void kloop(const short* __restrict__ wp, int nch,
                                      const short* Hh, int nt0, int quad, int l16,
                                      f32x4 (&acc)[MT][NTC]) {
#pragma unroll
    for (int mt = 0; mt < MT; ++mt)
#pragma unroll
        for (int i = 0; i < NTC; ++i)
#pragma unroll
            for (int r = 0; r < 4; ++r) acc[mt][i][r] = 0.0f;
#pragma unroll 1
    for (int c = 0; c < nch; ++c) {
        const short* cb = wp + (size_t)(c * 19 + nt0) * 1024 + quad * 128 + l16 * 8;
        short8 ah[MT];
#pragma unroll
        for (int mt = 0; mt < MT; ++mt)
            ah[mt] = *(const short8*)&Hh[(mt * 16 + l16) * KS + c * 32 + quad * 8];
        short8 bb[NTC];
#pragma unroll
        for (int i = 0; i < NTC; ++i) bb[i] = *(const short8*)(cb + (size_t)i * 1024);
#pragma unroll
        for (int mt = 0; mt < MT; ++mt)
#pragma unroll
            for (int i = 0; i < NTC; ++i)
                acc[mt][i] = MFMA_B16(ah[mt], bb[i], acc[mt][i]);
#pragma unroll
        for (int i = 0; i < NTC; ++i) bb[i] = *(const short8*)(cb + (size_t)i * 1024 + 512);
#pragma unroll
        for (int mt = 0; mt < MT; ++mt)
#pragma unroll
            for (int i = 0; i < NTC; ++i)
                acc[mt][i] = MFMA_B16(ah[mt], bb[i], acc[mt][i]);
    }
}

template <int MT, int NTC>
__device__ __forceinline__ void gcn_epilogue(const float* __restrict__ bias,
                                             int nt0, int quad, int l16,
                                             f32x4 (&acc)[MT][NTC], short* Hh) {
#pragma unroll
    for (int i = 0; i < NTC; ++i) {
        int c = (nt0 + i) * 16 + l16;
        float b = (c < HID) ? bias[c] : 0.0f;
#pragma unroll
        for (int mt = 0; mt < MT; ++mt)
#pragma unroll
            for (int r = 0; r < 4; ++r) {
                float v = fmaxf(acc[mt][i][r] + b, 0.0f);
                Hh[(mt * 16 + quad * 4 + r) * KS + c] = bf16r(v);
            }
    }
}

// final partB layer: column sums -> PLAIN per-block store (R10/R11 fix)
template <int MT, int NTC>
__device__ __forceinline__ void gcn_final(const float* __restrict__ bias,
                                          int nt0, int quad, int l16,
                                          f32x4 (&acc)[MT][NTC],
                                          float* __restrict__ gout) {
#pragma unroll
    for (int i = 0; i < NTC; ++i) {
        int c = (nt0 + i) * 16 + l16;
        float b = (c < HID) ? bias[c] : 0.0f;
        float s = 0.0f;
#pragma unroll
        for (int mt = 0; mt < MT; ++mt)
#pragma unroll
            for (int r = 0; r < 4; ++r) s += fmaxf(acc[mt][i][r] + b, 0.0f);
        s += __shfl_xor(s, 16, 64);
        s += __shfl_xor(s, 32, 64);
        if (quad == 0) gout[c] = (c < HID) ? s : 0.0f;
    }
}

template <int MT, int NTC>
__device__ __forceinline__ void gemm_out(int base, int nt0, int quad, int l16,
                                         f32x4 (&acc)[MT][NTC],
                                         unsigned short* __restrict__ HW) {
#pragma unroll
    for (int i = 0; i < NTC; ++i) {
        int c = (nt0 + i) * 16 + l16;
#pragma unroll
        for (int mt = 0; mt < MT; ++mt)
#pragma unroll
            for (int r = 0; r < 4; ++r) {
                int gm = base + mt * 16 + quad * 4 + r;
                if (gm < N_NODES)
                    HW[(size_t)gm * HIDP + c] = (unsigned short)bf16r(acc[mt][i][r]);
            }
    }
}

// ---------------------------------------------------------------------------
// k_mega: partB (1875, 80 rows, 5 M-tiles) U gemmA-L0 (125) U CSR-fill (313).
// (512,4): reg budget 128 (demand ~110: acc 60 AGPR + A 20 + B 12 + addr);
// LDS 52480 B -> 2 blocks/CU = 16 waves/CU. B L2 traffic 2.93 GB (was 4.87).
// ---------------------------------------------------------------------------
__global__ __launch_bounds__(512, 4) void k_mega(
    const float* __restrict__ edge_attr,
    const float* __restrict__ edge_w,
    const float* __restrict__ edge_b,
    const short* __restrict__ wt0,
    const short* __restrict__ wtl,
    const float* __restrict__ gcn0_b,
    const float* __restrict__ gcn_b,
    float* __restrict__ gpartB,      // [PARTB_BLOCKS][HIDP] plain partials
    unsigned short* __restrict__ hw0,
    const int* __restrict__ row,
    const int* __restrict__ col,
    int* __restrict__ cursor,
    const float* __restrict__ dinv,
    int2* __restrict__ edge_pack) {
    __shared__ short Hh[RBM * KS];   // 52480 B
    int bid = blockIdx.x, t = threadIdx.x;
    int lane = t & 63, w = t >> 6;
    int l16 = lane & 15, quad = lane >> 4;
    int nt0 = (w < 3) ? w * 3 : 9 + (w - 3) * 2;

    if (bid < PARTB_BLOCKS) {
        // ---------------- Part B unit (fused 5-layer), exact 80 rows -------
        int base = N_NODES + bid * RBM;
        for (int i = t; i < RBM * 8; i += 512) {
            int r = i >> 3, c4 = (i & 7) * 4;
            const float* ar = edge_attr + (size_t)(base + r) * 3;
            float a0 = ar[0], a1 = ar[1], a2 = ar[2];
#pragma unroll
            for (int j = 0; j < 4; ++j) {
                int cc = c4 + j;
                float v = edge_b[cc];
                v = fmaf(a0, edge_w[cc], v);
                v = fmaf(a1, edge_w[32 + cc], v);
                v = fmaf(a2, edge_w[64 + cc], v);
                Hh[r * KS + cc] = bf16r(v);
            }
        }
        for (int i = t; i < RBM * 24; i += 512) {
            int r = i / 24, k = 304 + i % 24;
            Hh[r * KS + k] = 0;
        }
        __syncthreads();

        float* gout = gpartB + (size_t)bid * HIDP;
        if (w < 3) {
            f32x4 acc[5][3];
            kloop<5, 3>(wt0, 1, Hh, nt0, quad, l16, acc);
            __syncthreads();
            gcn_epilogue<5, 3>(gcn0_b, nt0, quad, l16, acc, Hh);
            __syncthreads();
            for (int l = 0; l < 4; ++l) {
                kloop<5, 3>(wtl + (size_t)l * 194560, 10, Hh, nt0, quad, l16, acc);
                __syncthreads();
                if (l < 3) {
                    gcn_epilogue<5, 3>(gcn_b + l * HID, nt0, quad, l16, acc, Hh);
                    __syncthreads();
                } else {
                    gcn_final<5, 3>(gcn_b + l * HID, nt0, quad, l16, acc, gout);
                }
            }
        } else {
            f32x4 acc[5][2];
            kloop<5, 2>(wt0, 1, Hh, nt0, quad, l16, acc);
            __syncthreads();
            gcn_epilogue<5, 2>(gcn0_b, nt0, quad, l16, acc, Hh);
            __syncthreads();
            for (int l = 0; l < 4; ++l) {
                kloop<5, 2>(wtl + (size_t)l * 194560, 10, Hh, nt0, quad, l16, acc);
                __syncthreads();
                if (l < 3) {
                    gcn_epilogue<5, 2>(gcn_b + l * HID, nt0, quad, l16, acc, Hh);
                    __syncthreads();
                } else {
                    gcn_final<5, 2>(gcn_b + l * HID, nt0, quad, l16, acc, gout);
                }
            }
        }
    } else if (bid < PARTB_BLOCKS + GEMMA_BLOCKS) {
        // ---------------- Part A layer-0 GEMM (exact 125 x 80 rows) --------
        int base = (bid - PARTB_BLOCKS) * RBM;
        for (int i = t; i < RBM * 8; i += 512) {
            int r = i >> 3, c4 = (i & 7) * 4;
            const float* ar = edge_attr + (size_t)(base + r) * 3;
            float a0 = ar[0], a1 = ar[1], a2 = ar[2];
#pragma unroll
            for (int j = 0; j < 4; ++j) {
                int cc = c4 + j;
                float v = edge_b[cc];
                v = fmaf(a0, edge_w[cc], v);
                v = fmaf(a1, edge_w[32 + cc], v);
                v = fmaf(a2, edge_w[64 + cc], v);
                Hh[r * KS + cc] = bf16r(v);
            }
        }
        for (int i = t; i < RBM * 24; i += 512) {
            int r = i / 24, k = 304 + i % 24;
            Hh[r * KS + k] = 0;
        }
        __syncthreads();
        if (w < 3) {
            f32x4 acc[5][3];
            kloop<5, 3>(wt0, 1, Hh, nt0, quad, l16, acc);
            gemm_out<5, 3>(base, nt0, quad, l16, acc, hw0);
        } else {
            f32x4 acc[5][2];
            kloop<5, 2>(wt0, 1, Hh, nt0, quad, l16, acc);
            gemm_out<5, 2>(base, nt0, quad, l16, acc, hw0);
        }
    } else {
        // ---------------- CSR fill (row, norm) ----------------
        int e = (bid - PARTB_BLOCKS - GEMMA_BLOCKS) * 512 + t;
        if (e < N_EDGES) {
            int c = col[e], r = row[e];
            int p = atomicAdd(&cursor[c], 1);
            edge_pack[p] = make_int2(r, __float_as_int(dinv[r] * dinv[c]));
        }
    }
}

// ---------------------------------------------------------------------------
// agg of one node's neighbor sum into v[5] (R9-R11 verified)
// ---------------------------------------------------------------------------
__device__ __forceinline__ void agg_row(int c, int lane,
                                        const unsigned short* __restrict__ hw_in,
                                        const int* __restrict__ col_start,
                                        const int2* __restrict__ edge_pack,
                                        float (&v)[5]) {
#pragma unroll
    for (int jj = 0; jj < 5; ++jj) v[jj] = 0.0f;
    int beg = col_start[c], end = col_start[c + 1];
    int i = beg;
    for (; i + 4 <= end; i += 4) {
        int2 e0 = edge_pack[i], e1 = edge_pack[i + 1];
        int2 e2 = edge_pack[i + 2], e3 = edge_pack[i + 3];
        const unsigned short* h0 = hw_in + (size_t)e0.x * HIDP;
        const unsigned short* h1 = hw_in + (size_t)e1.x * HIDP;
        const unsigned short* h2 = hw_in + (size_t)e2.x * HIDP;
        const unsigned short* h3 = hw_in + (size_t)e3.x * HIDP;
        float n0 = __int_as_float(e0.y), n1 = __int_as_float(e1.y);
        float n2 = __int_as_float(e2.y), n3 = __int_as_float(e3.y);
#pragma unroll
        for (int jj = 0; jj < 5; ++jj) {
            int cc = lane + 64 * jj;
            if (cc < HIDP) {
                float s = v[jj];
                s = fmaf(n0, b2f(h0[cc]), s);
                s = fmaf(n1, b2f(h1[cc]), s);
                s = fmaf(n2, b2f(h2[cc]), s);
                s = fmaf(n3, b2f(h3[cc]), s);
                v[jj] = s;
            }
        }
    }
    for (; i < end; ++i) {
        int2 e0 = edge_pack[i];
        const unsigned short* h0 = hw_in + (size_t)e0.x * HIDP;
        float n0 = __int_as_float(e0.y);
#pragma unroll
        for (int jj = 0; jj < 5; ++jj) {
            int cc = lane + 64 * jj;
            if (cc < HIDP) v[jj] = fmaf(n0, b2f(h0[cc]), v[jj]);
        }
    }
}

// ---------------------------------------------------------------------------
// k_fuse: agg(prev hw) -> relu+bias -> LDS -> gemm -> next hw (R11-verified)
// ---------------------------------------------------------------------------
__global__ __launch_bounds__(512, 6) void k_fuse(
    const unsigned short* __restrict__ hw_in,
    const int* __restrict__ col_start,
    const int2* __restrict__ edge_pack,
    const float* __restrict__ selfnorm,
    const float* __restrict__ bias,
    const short* __restrict__ wt,
    unsigned short* __restrict__ hw_out) {
    __shared__ short Hh[RBF * KS];
    int t = threadIdx.x;
    int lane = t & 63, w = t >> 6;
    int l16 = lane & 15, quad = lane >> 4;
    int base = blockIdx.x * RBF;
    int nt0 = (w < 3) ? w * 3 : 9 + (w - 3) * 2;

#pragma unroll 1
    for (int j = 0; j < 4; ++j) {
        int r = w * 4 + j;
        int c = base + r;
        if (c < N_NODES) {
            float v[5];
            agg_row(c, lane, hw_in, col_start, edge_pack, v);
            float sn = selfnorm[c];
            const unsigned short* sp = hw_in + (size_t)c * HIDP;
#pragma unroll
            for (int jj = 0; jj < 5; ++jj) {
                int cc = lane + 64 * jj;
                if (cc < HIDP) {
                    float h = v[jj] + sn * b2f(sp[cc]) + ((cc < HID) ? bias[cc] : 0.0f);
                    Hh[r * KS + cc] = bf16r(fmaxf(h, 0.0f));
                }
            }
        } else {
#pragma unroll
            for (int jj = 0; jj < 5; ++jj) {
                int cc = lane + 64 * jj;
                if (cc < HIDP) Hh[r * KS + cc] = 0;
            }
        }
    }
    for (int i = t; i < RBF * 24; i += 512) {
        int r = i / 24, k = 304 + i % 24;
        Hh[r * KS + k] = 0;
    }
    __syncthreads();

    if (w < 3) {
        f32x4 acc[2][3];
        kloop<2, 3>(wt, 10, Hh, nt0, quad, l16, acc);
        gemm_out<2, 3>(base, nt0, quad, l16, acc, hw_out);
    } else {
        f32x4 acc[2][2];
        kloop<2, 2>(wt, 10, Hh, nt0, quad, l16, acc);
        gemm_out<2, 2>(base, nt0, quad, l16, acc, hw_out);
    }
}

// ---------------------------------------------------------------------------
// k_last: final Part-A agg + colsum into g_sum, with gpartB fold absorbed
// (waves 0..5 each add one gpartB row into their running sums — removes the
// separate k_gfold launch).
// ---------------------------------------------------------------------------
__global__ __launch_bounds__(512) void k_last(
    const unsigned short* __restrict__ hw_in,
    const int* __restrict__ col_start,
    const int2* __restrict__ edge_pack,
    const float* __restrict__ selfnorm,
    const float* __restrict__ bias,
    const float* __restrict__ gpartB,
    float* __restrict__ g_sum) {
    __shared__ float red[8 * 320];
    int t = threadIdx.x;
    int lane = t & 63, w = t >> 6;
    int base = blockIdx.x * RBF;

    float s[5] = {0.0f, 0.0f, 0.0f, 0.0f, 0.0f};
#pragma unroll 1
    for (int j = 0; j < 4; ++j) {
        int c = base + w * 4 + j;
        if (c < N_NODES) {
            float v[5];
            agg_row(c, lane, hw_in, col_start, edge_pack, v);
            float sn = selfnorm[c];
            const unsigned short* sp = hw_in + (size_t)c * HIDP;
#pragma unroll
            for (int jj = 0; jj < 5; ++jj) {
                int cc = lane + 64 * jj;
                if (cc < HID) {
                    float h = v[jj] + sn * b2f(sp[cc]) + bias[cc];
                    s[jj] += fmaxf(h, 0.0f);
                }
            }
        }
    }
    // fold partB per-block partials (6 rows per block; 313*6 >= 1875)
    if (w < 6) {
        int rr = blockIdx.x * 6 + w;
        if (rr < PARTB_BLOCKS) {
#pragma unroll
            for (int jj = 0; jj < 5; ++jj) {
                int cc = lane + 64 * jj;
                if (cc < HID) s[jj] += gpartB[(size_t)rr * HIDP + cc];
            }
        }
    }
#pragma unroll
    for (int jj = 0; jj < 5; ++jj) red[w * 320 + lane + 64 * jj] = s[jj];
    __syncthreads();
    if (w == 0) {
#pragma unroll
        for (int jj = 0; jj < 5; ++jj) {
            int cc = lane + 64 * jj;
            if (cc < HID) {
                float tot = 0.0f;
#pragma unroll
                for (int g = 0; g < 8; ++g) tot += red[g * 320 + cc];
                atomicAdd(&g_sum[cc], tot);
            }
        }
    }
}

__global__ void k_head(const float* __restrict__ g_sum,
                       const float* __restrict__ lin1_w, const float* __restrict__ lin1_b,
                       const float* __restrict__ lin2_w, const float* __restrict__ lin2_b,
                       float* __restrict__ out) {
    __shared__ float g2[32];
    int t = threadIdx.x;
    const float inv = 1.0f / (float)N_EDGES;
    if (t < 32) {
        float a = lin1_b[t];
        for (int d = 0; d < HID; ++d) a = fmaf(g_sum[d] * inv, lin1_w[d * 32 + t], a);
        g2[t] = fmaxf(a, 0.0f);
    }
    __syncthreads();
    if (t < 2) {
        float p = lin2_b[t];
        for (int j = 0; j < 32; ++j) p = fmaf(g2[j], lin2_w[j * 2 + t], p);
        out[t] = p;
    }
}

// ---------------------------------------------------------------------------

extern "C" void kernel_launch(void* const* d_in, const int* in_sizes, int n_in,
                              void* d_out, int out_size, void* d_ws, size_t ws_size,
                              hipStream_t stream) {
    (void)in_sizes; (void)n_in; (void)out_size; (void)ws_size;
    const int* edge_index = (const int*)d_in[1];
    const float* edge_attr = (const float*)d_in[2];
    const float* edge_w = (const float*)d_in[6];
    const float* edge_b = (const float*)d_in[7];
    const float* gcn0_w = (const float*)d_in[8];
    const float* gcn0_b = (const float*)d_in[9];
    const float* gcn_w = (const float*)d_in[10];
    const float* gcn_b = (const float*)d_in[11];
    const float* lin1_w = (const float*)d_in[12];
    const float* lin1_b = (const float*)d_in[13];
    const float* lin2_w = (const float*)d_in[14];
    const float* lin2_b = (const float*)d_in[15];

    char* ws = (char*)d_ws;
    size_t off = 0;
    auto alloc = [&](size_t bytes) {
        void* p = ws + off;
        off = (off + bytes + 255) & ~(size_t)255;
        return p;
    };
    unsigned short* hwA = (unsigned short*)alloc((size_t)N_NODES * HIDP * 2);
    unsigned short* hwB = (unsigned short*)alloc((size_t)N_NODES * HIDP * 2);
    int2* edge_pack = (int2*)alloc((size_t)N_EDGES * 8);
    int* cnt = (int*)alloc((size_t)N_NODES * 4);
    int* col_start = (int*)alloc((size_t)(N_NODES + 1) * 4);
    int* cursor = (int*)alloc((size_t)N_NODES * 4);
    float* dinv = (float*)alloc((size_t)N_NODES * 4);
    float* selfnorm = (float*)alloc((size_t)N_NODES * 4);
    float* g_sum = (float*)alloc((size_t)HIDP * 4);
    short* wt0 = (short*)alloc((size_t)38912);
    short* wtl = (short*)alloc((size_t)4 * 389120);
    float* gpartB = (float*)alloc((size_t)PARTB_BLOCKS * HIDP * 4);

    const int* row = edge_index;
    const int* col = edge_index + N_EDGES;

    hipMemsetAsync(cnt, 0, N_NODES * 4, stream);
    hipMemsetAsync(g_sum, 0, HIDP * 4, stream);

    k_prep<<<(N_EDGES + 255) / 256, 256, 0, stream>>>(gcn0_w, gcn_w, wt0, wtl, col, cnt);
    k_scan<<<1, 1024, 0, stream>>>(cnt, col_start, cursor, dinv, selfnorm);

    // mega: partB (80-row blocks, L2-B traffic 2.93 GB) + Part-A L0 + CSR fill
    k_mega<<<MEGA_BLOCKS, 512, 0, stream>>>(edge_attr, edge_w, edge_b, wt0, wtl,
                                            gcn0_b, gcn_b, gpartB, hwA,
                                            row, col, cursor, dinv, edge_pack);

    // Part A layers 1..4: fused agg+gemm per layer (313 blocks each)
    k_fuse<<<FUSE_BLOCKS, 512, 0, stream>>>(hwA, col_start, edge_pack, selfnorm,
                                            gcn0_b, wtl + (size_t)0 * 194560, hwB);
    k_fuse<<<FUSE_BLOCKS, 512, 0, stream>>>(hwB, col_start, edge_pack, selfnorm,
                                            gcn_b + 0 * HID, wtl + (size_t)1 * 194560, hwA);
    k_fuse<<<FUSE_BLOCKS, 512, 0, stream>>>(hwA, col_start, edge_pack, selfnorm,
                                            gcn_b + 1 * HID, wtl + (size_t)2 * 194560, hwB);
    k_fuse<<<FUSE_BLOCKS, 512, 0, stream>>>(hwB, col_start, edge_pack, selfnorm,
                                            gcn_b + 2 * HID, wtl + (size_t)3 * 194560, hwA);
    // final agg + colsum + partB fold, then head
    k_last<<<FUSE_BLOCKS, 512, 0, stream>>>(hwA, col_start, edge_pack, selfnorm,
                                            gcn_b + 3 * HID, gpartB, g_sum);
    k_head<<<1, 64, 0, stream>>>(g_sum, lin1_w, lin1_b, lin2_w, lin2_b, (float*)d_out);
}